// Round 8
// baseline (388.434 us; speedup 1.0000x reference)
//
#include <hip/hip_runtime.h>
#include <hip/hip_bf16.h>
#include <math.h>

#define N_NODES 10000
#define N_PAD   10048       // 157 * 64
#define N_EDGES 320000
#define DIM     176
#define ATT     16
#define SH_HEADS 16
#define THH     4
#define NH      20          // SH_HEADS + TH
#define VD      11          // DIM / SH_HEADS
#define ZDIM    16
#define RDIM    16
#define QK_W    (NH*ATT)    // 320
#define QKV_W   816         // 320+320+176
#define UI_W    (2*DIM)     // 352
#define KQ      192         // padded K for qkv gemm
#define SIGINV  3.5714285714285716f   // (RDIM-1)/(CUT-RSTART)
#define RSTEP   0.28f                 // (CUT-RSTART)/(RDIM-1)

typedef unsigned short ushort_t;
typedef __attribute__((ext_vector_type(8))) short bf16x8;
typedef __attribute__((ext_vector_type(4))) float f32x4;

// ---------------- helpers ----------------

__device__ __forceinline__ ushort_t f2bf(float f) {
    __hip_bfloat16 b = __float2bfloat16(f);
    return *(ushort_t*)&b;
}

__device__ __forceinline__ float bf2f(ushort_t u) {
    return __uint_as_float(((unsigned)u) << 16);
}

__device__ __forceinline__ void sph16(float x, float y, float z, float* Y) {
    const float s3  = 1.7320508075688772f;
    const float s15 = 3.872983346207417f;
    const float c1  = 0.7905694150420949f;
    const float c2  = 0.6123724356957945f;
    float x2 = x*x, y2 = y*y, z2 = z*z;
    Y[0]  = 1.0f;
    Y[1]  = x;
    Y[2]  = y;
    Y[3]  = z;
    Y[4]  = s3 * x * y;
    Y[5]  = s3 * y * z;
    Y[6]  = 0.5f * (3.0f * z2 - 1.0f);
    Y[7]  = s3 * x * z;
    Y[8]  = 0.5f * s3 * (x2 - y2);
    Y[9]  = c1 * y * (3.0f * x2 - y2);
    Y[10] = s15 * x * y * z;
    Y[11] = c2 * y * (5.0f * z2 - 1.0f);
    Y[12] = 0.5f * z * (5.0f * z2 - 3.0f);
    Y[13] = c2 * x * (5.0f * z2 - 1.0f);
    Y[14] = 0.5f * s15 * z * (x2 - y2);
    Y[15] = c1 * x * (x2 - 3.0f * y2);
}

__device__ __forceinline__ void unpack8(const uint4 u, float* f) {
    f[0] = __uint_as_float(u.x << 16);
    f[1] = __uint_as_float(u.x & 0xffff0000u);
    f[2] = __uint_as_float(u.y << 16);
    f[3] = __uint_as_float(u.y & 0xffff0000u);
    f[4] = __uint_as_float(u.z << 16);
    f[5] = __uint_as_float(u.z & 0xffff0000u);
    f[6] = __uint_as_float(u.w << 16);
    f[7] = __uint_as_float(u.w & 0xffff0000u);
}

// ---------------- merged prologue: deg+pack | weight prep | node embed ------

__device__ __forceinline__ void deg_body(int bid, int tid,
        const int* __restrict__ edst, const int* __restrict__ esrc,
        const float* __restrict__ dist, const float* __restrict__ swit,
        const float* __restrict__ vec, int* deg, int* rank, uint4* pk) {
    int e = bid * 256 + tid;
    if (e >= N_EDGES) return;
    int t_ = edst[e];
    rank[e] = atomicAdd(&deg[t_], 1);
    uint4 a, b;
    a.x = (unsigned)esrc[e];
    a.y = (unsigned)t_;
    a.z = __float_as_uint(dist[e]);
    a.w = __float_as_uint(swit[e]);
    b.x = __float_as_uint(vec[(size_t)e*3 + 0]);
    b.y = __float_as_uint(vec[(size_t)e*3 + 1]);
    b.z = __float_as_uint(vec[(size_t)e*3 + 2]);
    b.w = 0u;
    pk[(size_t)e*2 + 0] = a;
    pk[(size_t)e*2 + 1] = b;
}

__device__ __forceinline__ void prep_qkv_body(int bid, int tid, const float* wq,
        const float* wk, const float* wv, ushort_t* Wtq) {
    int id = bid * 256 + tid;
    if (id >= 832 * KQ) return;
    int n = id / KQ, k = id - (id / KQ) * KQ;
    float v = 0.0f;
    if (k < DIM && n < QKV_W)
        v = (n < 320) ? wq[k * 320 + n] : (n < 640) ? wk[k * 320 + (n - 320)]
                                                    : wv[k * DIM + (n - 640)];
    Wtq[id] = f2bf(v);
}

__device__ __forceinline__ void prep_upd_body(int bid, int tid, const float* uw, ushort_t* Wtu) {
    int id = bid * 256 + tid;
    if (id >= 192 * UI_W) return;
    int n = id / UI_W, k = id - (id / UI_W) * UI_W;
    float v = (n < DIM) ? uw[k * DIM + n] : 0.0f;
    Wtu[id] = f2bf(v);
}

__device__ __forceinline__ void prep_mlp_body(int bid, int tid, const float* pw1,
        const float* pw2, ushort_t* w1T, ushort_t* w2T, int K1) {
    int id = bid * 256 + tid;
    if (id < 1024) {
        int n = id >> 5, k = id & 31;
        w1T[n * 32 + k] = (k < K1) ? f2bf(pw1[k * 32 + n]) : 0;
    } else if (id < 1536) {
        int id2 = id - 1024;
        int n = id2 >> 5, k = id2 & 31;
        w2T[n * 32 + k] = f2bf(pw2[k * 16 + n]);
    }
}

struct InitSmem {
    float zs[16 * ZDIM];
    float yt[16 * DIM];
    float red[256];
    float mus[16], rstds[16];
};

__device__ void init_body(int bid, int tid, InitSmem& sm,
        const int* species, const float* z_table, const float* wsp,
        float* xi, ushort_t* xib, ushort_t* cxm) {
    int base = bid * 16;
    { int n = tid >> 4, kk = tid & 15;
      sm.zs[tid] = z_table[species[base + n] * ZDIM + kk]; }
    __syncthreads();
    int c = tid;
    if (c < DIM) {
        float acc[16];
        #pragma unroll
        for (int n = 0; n < 16; n++) acc[n] = 0.0f;
        for (int kk = 0; kk < ZDIM; kk++) {
            float w = wsp[kk * DIM + c];
            #pragma unroll
            for (int n = 0; n < 16; n++) acc[n] += sm.zs[n * ZDIM + kk] * w;
        }
        #pragma unroll
        for (int n = 0; n < 16; n++) sm.yt[n * DIM + c] = acc[n];
    }
    __syncthreads();
    { int n2 = tid >> 4, j = tid & 15;
      float s = 0.0f;
      for (int c2 = j; c2 < DIM; c2 += 16) s += sm.yt[n2 * DIM + c2];
      sm.red[tid] = s; }
    __syncthreads();
    if (tid < 16) { float s = 0; for (int j = 0; j < 16; j++) s += sm.red[tid * 16 + j]; sm.mus[tid] = s / (float)DIM; }
    __syncthreads();
    { int n2 = tid >> 4, j = tid & 15;
      float mu = sm.mus[n2], s = 0.0f;
      for (int c2 = j; c2 < DIM; c2 += 16) { float d = sm.yt[n2 * DIM + c2] - mu; s += d * d; }
      sm.red[tid] = s; }
    __syncthreads();
    if (tid < 16) { float s = 0; for (int j = 0; j < 16; j++) s += sm.red[tid * 16 + j]; sm.rstds[tid] = rsqrtf(s / (float)DIM + 1e-6f); }
    __syncthreads();
    if (c < DIM) {
        #pragma unroll
        for (int n = 0; n < 16; n++) {
            float val = (sm.yt[n * DIM + c] - sm.mus[n]) * sm.rstds[n];
            xi[(size_t)(base + n) * DIM + c] = val;
            ushort_t bv = f2bf(val);
            xib[(size_t)(base + n) * KQ + c]   = bv;
            cxm[(size_t)(base + n) * UI_W + c] = bv;
        }
    } else if (c < KQ) {
        #pragma unroll
        for (int n = 0; n < 16; n++) xib[(size_t)(base + n) * KQ + c] = 0;
    }
}

// grid = 1250 (deg) + 1788 (prep) + 625 (node init) = 3663
__global__ __launch_bounds__(256) void k_pre(
        const int* edst, const int* esrc, const float* dist, const float* swit,
        const float* vec, int* deg, int* rank, uint4* pk,
        const float* wq0, const float* wk0, const float* wv0, ushort_t* Wtq0,
        const float* wq1, const float* wk1, const float* wv1, ushort_t* Wtq1,
        const float* uw0, ushort_t* Wtu0, const float* uw1, ushort_t* Wtu1,
        const float* pw1_0, const float* pw2_0, ushort_t* w1T0, ushort_t* w2T0,
        const float* pw1_1, const float* pw2_1, ushort_t* w1T1, ushort_t* w2T1,
        const int* species, const float* z_table, const float* wsp,
        float* xi, ushort_t* xib, ushort_t* cxm) {
    __shared__ InitSmem sm;
    int bid = blockIdx.x, tid = threadIdx.x;
    if (bid < 1250)       deg_body(bid, tid, edst, esrc, dist, swit, vec, deg, rank, pk);
    else if (bid < 1874)  prep_qkv_body(bid - 1250, tid, wq0, wk0, wv0, Wtq0);
    else if (bid < 2498)  prep_qkv_body(bid - 1874, tid, wq1, wk1, wv1, Wtq1);
    else if (bid < 2762)  prep_upd_body(bid - 2498, tid, uw0, Wtu0);
    else if (bid < 3026)  prep_upd_body(bid - 2762, tid, uw1, Wtu1);
    else if (bid < 3032)  prep_mlp_body(bid - 3026, tid, pw1_0, pw2_0, w1T0, w2T0, 16);
    else if (bid < 3038)  prep_mlp_body(bid - 3032, tid, pw1_1, pw2_1, w1T1, w2T1, 32);
    else                  init_body(bid - 3038, tid, sm, species, z_table, wsp, xi, xib, cxm);
}

// ---------------- single-block scan (deg -> off) ----------------

__global__ __launch_bounds__(1024) void k_scan(const int* __restrict__ deg, int* off) {
    __shared__ int sd[1024];
    int tid = threadIdx.x;
    int base = tid * 10;
    int v[10];
    int s = 0;
    #pragma unroll
    for (int j = 0; j < 10; j++) {
        int gi = base + j;
        v[j] = (gi < N_NODES) ? deg[gi] : 0;
        s += v[j];
    }
    sd[tid] = s;
    __syncthreads();
    for (int st = 1; st < 1024; st <<= 1) {
        int add = (tid >= st) ? sd[tid - st] : 0;
        __syncthreads();
        sd[tid] += add;
        __syncthreads();
    }
    int run = (tid > 0) ? sd[tid - 1] : 0;
    #pragma unroll
    for (int j = 0; j < 10; j++) {
        run += v[j];
        int gi = base + j;
        if (gi < N_NODES) off[gi + 1] = run;
    }
    if (tid == 0) off[0] = 0;
}

// scatter ONLY the 4-byte permutation index (CSR slot -> original edge)
__global__ __launch_bounds__(256) void k_perm(const int* edst, const int* rank,
                                              const int* off, int* perm) {
    int e = blockIdx.x * 256 + threadIdx.x;
    if (e >= N_EDGES) return;
    perm[off[edst[e]] + rank[e]] = e;
}

// thread = CSR slot: ONE random aligned 32 B read, fully coalesced writes
__global__ __launch_bounds__(256) void k_build(const int* __restrict__ perm,
        const uint4* __restrict__ pk,
        int* src_c, int* dst_c, float* dist_c, float* sc_c, float* Yf) {
    int p = blockIdx.x * 256 + threadIdx.x;
    if (p >= N_EDGES) return;
    int e  = perm[p];
    uint4 a = pk[(size_t)e*2 + 0];
    uint4 b = pk[(size_t)e*2 + 1];
    int s  = (int)a.x;
    int t_ = (int)a.y;
    float d  = __uint_as_float(a.z);
    float sw = __uint_as_float(a.w);
    float inv = 1.0f / d;
    float vx = __uint_as_float(b.x) * inv;
    float vy = __uint_as_float(b.y) * inv;
    float vz = __uint_as_float(b.z) * inv;
    src_c[p]  = s;
    dst_c[p]  = t_;
    dist_c[p] = d;
    sc_c[p]   = sw * 0.25f;               // switch / sqrt(ATT)
    float Y[16];
    sph16(vx, vy, vz, Y);
    #pragma unroll
    for (int m = 0; m < 16; m += 4)
        *(float4*)&Yf[(size_t)p * 16 + m] = make_float4(Y[m], Y[m+1], Y[m+2], Y[m+3]);
}

// ---------------- MFMA GEMM (QKV, K=192, single-stage full-K tiles) --------

__global__ __launch_bounds__(256) void k_gemmq(const ushort_t* __restrict__ A,
                                               const ushort_t* __restrict__ Bt,
                                               ushort_t* __restrict__ qh,
                                               ushort_t* __restrict__ kh,
                                               ushort_t* __restrict__ vh) {
    __shared__ ushort_t As[64 * 200];
    __shared__ ushort_t Bs[64 * 200];
    int tid  = threadIdx.x;
    int m0   = blockIdx.y * 64, n0 = blockIdx.x * 64;
    int w    = tid >> 6, lane = tid & 63, quad = lane >> 4, c16 = lane & 15;
    #pragma unroll
    for (int it = 0; it < 6; it++) {
        int seg = it * 256 + tid;
        int r = seg / 24, cs = seg - (seg / 24) * 24;
        *(uint4*)&As[r * 200 + cs * 8] =
            *(const uint4*)&A[(size_t)(m0 + r) * KQ + cs * 8];
        *(uint4*)&Bs[r * 200 + cs * 8] =
            *(const uint4*)&Bt[(size_t)(n0 + r) * KQ + cs * 8];
    }
    __syncthreads();
    f32x4 acc[4] = {};
    #pragma unroll
    for (int kc = 0; kc < 6; kc++) {
        bf16x8 a = *(const bf16x8*)&As[(w * 16 + c16) * 200 + kc * 32 + quad * 8];
        #pragma unroll
        for (int t = 0; t < 4; t++) {
            bf16x8 b = *(const bf16x8*)&Bs[(t * 16 + c16) * 200 + kc * 32 + quad * 8];
            acc[t] = __builtin_amdgcn_mfma_f32_16x16x32_bf16(a, b, acc[t], 0, 0, 0);
        }
    }
    #pragma unroll
    for (int t = 0; t < 4; t++) {
        #pragma unroll
        for (int r = 0; r < 4; r++) {
            int row = m0 + w * 16 + quad * 4 + r;
            int col = n0 + t * 16 + c16;
            if (row < N_NODES && col < QKV_W) {
                ushort_t bv = f2bf(acc[t][r]);
                if (col < 320)      qh[(size_t)row * QK_W + col] = bv;
                else if (col < 640) kh[(size_t)row * QK_W + (col - 320)] = bv;
                else                vh[(size_t)row * DIM  + (col - 640)] = bv;
            }
        }
    }
}

// ---------------- fused UPD GEMM + LayerNorm ----------------
// Block = 64 node rows. Whole K=352 A-tile staged in LDS (one barrier);
// B fragments read directly from the L2-resident 135 KB weight table.
// LN done fully in-register via shfl_xor over the 16 c16 lanes.

__global__ __launch_bounds__(256) void k_updln(const ushort_t* __restrict__ A,
        const ushort_t* __restrict__ Bt, const float* __restrict__ xi,
        const float* __restrict__ ub,
        float* xo, ushort_t* xib, ushort_t* cxm) {
    __shared__ ushort_t As[64 * 360];
    int tid  = threadIdx.x;
    int m0   = blockIdx.x * 64;
    int w    = tid >> 6, lane = tid & 63, quad = lane >> 4, c16 = lane & 15;
    // stage A: 64 rows x 352 cols = 2816 uint4 segs = 11 * 256
    #pragma unroll
    for (int it = 0; it < 11; it++) {
        int seg = it * 256 + tid;
        int r = seg / 44, cs = seg - (seg / 44) * 44;
        *(uint4*)&As[r * 360 + cs * 8] =
            *(const uint4*)&A[(size_t)(m0 + r) * UI_W + cs * 8];
    }
    __syncthreads();
    f32x4 acc[11] = {};
    for (int kc = 0; kc < 11; kc++) {
        bf16x8 a = *(const bf16x8*)&As[(w * 16 + c16) * 360 + kc * 32 + quad * 8];
        #pragma unroll
        for (int t = 0; t < 11; t++) {
            bf16x8 b = *(const bf16x8*)&Bt[(size_t)(t * 16 + c16) * UI_W + kc * 32 + quad * 8];
            acc[t] = __builtin_amdgcn_mfma_f32_16x16x32_bf16(a, b, acc[t], 0, 0, 0);
        }
    }
    float ubv[11];
    #pragma unroll
    for (int t = 0; t < 11; t++) ubv[t] = ub[t * 16 + c16];
    int rowb = m0 + w * 16 + quad * 4;
    #pragma unroll
    for (int r = 0; r < 4; r++) {
        int row = rowb + r;
        if (row >= N_NODES) continue;     // uniform across the 16-lane shfl group
        float srow = 0.0f;
        #pragma unroll
        for (int t = 0; t < 11; t++) {
            float val = acc[t][r] + xi[(size_t)row * DIM + t * 16 + c16] + ubv[t];
            acc[t][r] = val;
            srow += val;
        }
        srow += __shfl_xor(srow, 1);
        srow += __shfl_xor(srow, 2);
        srow += __shfl_xor(srow, 4);
        srow += __shfl_xor(srow, 8);
        float mu = srow / (float)DIM;
        float sv = 0.0f;
        #pragma unroll
        for (int t = 0; t < 11; t++) { float d = acc[t][r] - mu; sv += d * d; }
        sv += __shfl_xor(sv, 1);
        sv += __shfl_xor(sv, 2);
        sv += __shfl_xor(sv, 4);
        sv += __shfl_xor(sv, 8);
        float rstd = rsqrtf(sv / (float)DIM + 1e-6f);
        #pragma unroll
        for (int t = 0; t < 11; t++) {
            int col = t * 16 + c16;
            float nv = (acc[t][r] - mu) * rstd;
            xo[(size_t)row * DIM + col] = nv;
            ushort_t bv = f2bf(nv);
            xib[(size_t)row * KQ + col]   = bv;
            cxm[(size_t)row * UI_W + col] = bv;
        }
    }
}

// ---------------- fused edge kernel ----------------

template<bool L0>
__global__ __launch_bounds__(256) void k_edge(const float* dist_c, const float* sc_c,
        const int* src_c, const int* dst_c, const float* Yf, const ushort_t* Vih,
        const ushort_t* qh, const ushort_t* kh,
        const ushort_t* w1T, const float* pb1, const ushort_t* w2T, const float* pb2,
        ushort_t* aijh) {
    __shared__ ushort_t urS[64 * 40];
    __shared__ ushort_t Ht[4][16 * 40];
    __shared__ float    wdS[64 * 17];
    __shared__ ushort_t aS[NH][64];
    int tid  = threadIdx.x;
    int w    = tid >> 6, lane = tid & 63, quad = lane >> 4, c16 = lane & 15;
    int eb   = blockIdx.x * 64;

    // aij-phase mapping (known at entry; only depends on src_c/dst_c)
    int le = tid >> 2, part = tid & 3;
    int ie = eb + le;
    int sE = src_c[ie], tE = dst_c[ie];

    if (!L0) {
        int e  = tid & 63, tp = tid >> 6;   // 4 threads/edge: tp = th component
        int i  = eb + e;
        float d = dist_c[i];
        ushort_t ur4[4];
        #pragma unroll
        for (int r0 = 0; r0 < 4; r0++) {
            int r = tp * 4 + r0;
            float cc = 0.8f + (float)r * RSTEP;
            float uu = (d - cc) * SIGINV;
            ur4[r0] = f2bf(__expf(-uu * uu));
        }
        *(uint2*)&urS[e * 40 + tp * 4] = *(uint2*)ur4;
        float Y[16];
        #pragma unroll
        for (int m = 0; m < 16; m += 4) {
            float4 y = *(const float4*)&Yf[(size_t)i * 16 + m];
            Y[m] = y.x; Y[m+1] = y.y; Y[m+2] = y.z; Y[m+3] = y.w;
        }
        int s = src_c[i], t_ = dst_c[i];
        const uint4* vd4 = (const uint4*)(Vih + (size_t)t_ * 64);
        const uint4* vs4 = (const uint4*)(Vih + (size_t)s  * 64);
        int th = tp;
        float fd[16], fs[16];
        unpack8(vd4[2*th],   fd);     unpack8(vd4[2*th+1], fd+8);
        unpack8(vs4[2*th],   fs);     unpack8(vs4[2*th+1], fs+8);
        float us0 = (fd[0] + fs[0]) * Y[0];
        float us1 = 0.0f, us2 = 0.0f, us3 = 0.0f;
        #pragma unroll
        for (int m = 1; m < 4; m++)  us1 += (fd[m] - fs[m]) * Y[m];
        #pragma unroll
        for (int m = 4; m < 9; m++)  us2 += (fd[m] + fs[m]) * Y[m];
        #pragma unroll
        for (int m = 9; m < 16; m++) us3 += (fd[m] - fs[m]) * Y[m];
        urS[e * 40 + 16 + 0 * 4 + th] = f2bf(us0);
        urS[e * 40 + 16 + 1 * 4 + th] = f2bf(us1);
        urS[e * 40 + 16 + 2 * 4 + th] = f2bf(us2);
        urS[e * 40 + 16 + 3 * 4 + th] = f2bf(us3);
        __syncthreads();
    }

    // ---- k prefetch: 160 B contiguous segment of k[src], 10 x uint4 ----
    uint4 kr[10];
    {
        const uint4* kseg = (const uint4*)(kh + (size_t)sE * QK_W) + part * 10;
        #pragma unroll
        for (int j = 0; j < 10; j++) kr[j] = kseg[j];
    }

    {
        int e0 = eb + w * 16;
        bf16x8 a1;
        if (L0) {
            float d = dist_c[e0 + c16];
            #pragma unroll
            for (int j = 0; j < 8; j++) {
                int r = quad * 8 + j;
                float v = 0.0f;
                if (r < 16) { float cc = 0.8f + (float)r * RSTEP; float uu = (d - cc) * SIGINV; v = __expf(-uu * uu); }
                a1[j] = (short)f2bf(v);
            }
        } else {
            a1 = *(const bf16x8*)&urS[(w * 16 + c16) * 40 + quad * 8];
        }
        bf16x8 b0 = *(const bf16x8*)&w1T[c16 * 32 + quad * 8];
        bf16x8 b1 = *(const bf16x8*)&w1T[(16 + c16) * 32 + quad * 8];
        f32x4 acc0 = {}, acc1 = {};
        acc0 = __builtin_amdgcn_mfma_f32_16x16x32_bf16(a1, b0, acc0, 0, 0, 0);
        acc1 = __builtin_amdgcn_mfma_f32_16x16x32_bf16(a1, b1, acc1, 0, 0, 0);
        float bb0 = pb1[c16], bb1 = pb1[c16 + 16];
        #pragma unroll
        for (int r = 0; r < 4; r++) {
            int er = quad * 4 + r;
            float h0 = acc0[r] + bb0; h0 = h0 / (1.0f + __expf(-h0));
            float h1 = acc1[r] + bb1; h1 = h1 / (1.0f + __expf(-h1));
            Ht[w][er * 40 + c16]      = f2bf(h0);
            Ht[w][er * 40 + 16 + c16] = f2bf(h1);
        }
        __syncthreads();
        bf16x8 a2 = *(const bf16x8*)&Ht[w][c16 * 40 + quad * 8];
        bf16x8 b2 = *(const bf16x8*)&w2T[c16 * 32 + quad * 8];
        f32x4 acc2 = {};
        acc2 = __builtin_amdgcn_mfma_f32_16x16x32_bf16(a2, b2, acc2, 0, 0, 0);
        float bb2 = pb2[c16];
        #pragma unroll
        for (int r = 0; r < 4; r++) {
            int er = quad * 4 + r;
            wdS[(w * 16 + er) * 17 + c16] = (acc2[r] + bb2) * sc_c[e0 + er];
        }
    }
    __syncthreads();

    {
        float wd[16];
        #pragma unroll
        for (int p = 0; p < 16; p++) wd[p] = wdS[le * 17 + p];
        const uint4* q4 = (const uint4*)(qh + (size_t)tE * QK_W) + part * 10;
        #pragma unroll
        for (int j = 0; j < 5; j++) {
            int h = part * 5 + j;
            float qa[8], qb[8], ka[8], kb[8];
            unpack8(q4[2*j],   qa); unpack8(q4[2*j+1], qb);
            unpack8(kr[2*j],   ka); unpack8(kr[2*j+1], kb);
            float acc = 0.0f;
            #pragma unroll
            for (int dd = 0; dd < 8; dd++) acc += qa[dd] * ka[dd] * wd[dd];
            #pragma unroll
            for (int dd = 0; dd < 8; dd++) acc += qb[dd] * kb[dd] * wd[8 + dd];
            aS[h][le] = f2bf(acc);
        }
    }
    __syncthreads();
    {
        const uint* aSw = (const uint*)aS;
        for (int idx = tid; idx < NH * 32; idx += 256) {
            int h = idx >> 5, w2 = idx & 31;
            *(uint*)(aijh + (size_t)h * N_EDGES + eb + w2 * 2) = aSw[h * 32 + w2];
        }
    }
}

// ---------------- aggregation: one wave per node for BOTH mi and Vi ----------

__device__ __forceinline__ void mi_step(int i, int c0, bool f1, bool f2,
        const int* src_c, const ushort_t* aA, const ushort_t* aB, const ushort_t* vh,
        float& acc0, float& acc1, float& acc2, float& acc3) {
    int s0 = src_c[i];
    uint2 v0 = *(const uint2*)(vh + (size_t)s0 * DIM + c0);
    float a00 = bf2f(aA[i]), a0B = bf2f(aB[i]);
    float g01 = f1 ? a0B : a00, g02 = f2 ? a0B : a00;
    acc0 += a00 * __uint_as_float(v0.x << 16);
    acc1 += g01 * __uint_as_float(v0.x & 0xffff0000u);
    acc2 += g02 * __uint_as_float(v0.y << 16);
    acc3 += a0B * __uint_as_float(v0.y & 0xffff0000u);
}

// software-pipelined: load chunk c+1 (srcs, v-rows, aij) while computing chunk c
__device__ __forceinline__ void mi_wave(int n, int lane, const int* off, const int* src_c,
        const ushort_t* aijh, const ushort_t* vh, ushort_t* cxm) {
    if (lane >= 44) return;
    int c0 = lane * 4;
    int hA = c0 / VD;
    int hB = (c0 + 3) / VD;
    bool f1 = ((c0 + 1) / VD) != hA;
    bool f2 = ((c0 + 2) / VD) != hA;
    const ushort_t* aA = aijh + (size_t)hA * N_EDGES;
    const ushort_t* aB = aijh + (size_t)hB * N_EDGES;
    int start = off[n], end = off[n + 1];
    float acc0 = 0, acc1 = 0, acc2 = 0, acc3 = 0;
    int cnt = end - start;
    int i = start;

#define MI_ACC(vv, av, bv) { \
    float aa = bf2f(av), ab = bf2f(bv); \
    float g1 = f1 ? ab : aa, g2 = f2 ? ab : aa; \
    acc0 += aa * __uint_as_float((vv).x << 16); \
    acc1 += g1 * __uint_as_float((vv).x & 0xffff0000u); \
    acc2 += g2 * __uint_as_float((vv).y << 16); \
    acc3 += ab * __uint_as_float((vv).y & 0xffff0000u); }

    if (cnt >= 4) {
        int iend = start + (cnt & ~3);
        int s0 = src_c[i], s1 = src_c[i+1], s2 = src_c[i+2], s3 = src_c[i+3];
        uint2 v0 = *(const uint2*)(vh + (size_t)s0 * DIM + c0);
        uint2 v1 = *(const uint2*)(vh + (size_t)s1 * DIM + c0);
        uint2 v2 = *(const uint2*)(vh + (size_t)s2 * DIM + c0);
        uint2 v3 = *(const uint2*)(vh + (size_t)s3 * DIM + c0);
        ushort_t pA0 = aA[i], pA1 = aA[i+1], pA2 = aA[i+2], pA3 = aA[i+3];
        ushort_t pB0 = aB[i], pB1 = aB[i+1], pB2 = aB[i+2], pB3 = aB[i+3];
        for (i += 4; i + 4 <= iend; i += 4) {
            int t0 = src_c[i], t1 = src_c[i+1], t2 = src_c[i+2], t3 = src_c[i+3];
            uint2 w0 = *(const uint2*)(vh + (size_t)t0 * DIM + c0);
            uint2 w1 = *(const uint2*)(vh + (size_t)t1 * DIM + c0);
            uint2 w2 = *(const uint2*)(vh + (size_t)t2 * DIM + c0);
            uint2 w3 = *(const uint2*)(vh + (size_t)t3 * DIM + c0);
            ushort_t qA0 = aA[i], qA1 = aA[i+1], qA2 = aA[i+2], qA3 = aA[i+3];
            ushort_t qB0 = aB[i], qB1 = aB[i+1], qB2 = aB[i+2], qB3 = aB[i+3];
            MI_ACC(v0, pA0, pB0); MI_ACC(v1, pA1, pB1);
            MI_ACC(v2, pA2, pB2); MI_ACC(v3, pA3, pB3);
            v0 = w0; v1 = w1; v2 = w2; v3 = w3;
            pA0 = qA0; pA1 = qA1; pA2 = qA2; pA3 = qA3;
            pB0 = qB0; pB1 = qB1; pB2 = qB2; pB3 = qB3;
        }
        MI_ACC(v0, pA0, pB0); MI_ACC(v1, pA1, pB1);
        MI_ACC(v2, pA2, pB2); MI_ACC(v3, pA3, pB3);
    }
    for (; i < end; i++)
        mi_step(i, c0, f1, f2, src_c, aA, aB, vh, acc0, acc1, acc2, acc3);
#undef MI_ACC
    ushort_t o[4] = {f2bf(acc0), f2bf(acc1), f2bf(acc2), f2bf(acc3)};
    *(uint2*)(cxm + (size_t)n * UI_W + DIM + c0) = *(uint2*)o;
}

// software-pipelined vi reduction
__device__ __forceinline__ void vi_wave(int n, int lane, const int* off,
        const float* Yf, const ushort_t* aijh, ushort_t* Vih) {
    int th = lane >> 4, sm = lane & 15;
    const ushort_t* ah = aijh + (size_t)(SH_HEADS + th) * N_EDGES;
    int start = off[n], end = off[n + 1];
    float acc = 0.0f;
    int cnt = end - start;
    int i = start;
    if (cnt >= 4) {
        int iend = start + (cnt & ~3);
        float a0 = bf2f(ah[i]),   y0 = Yf[(size_t)i * 16 + sm];
        float a1 = bf2f(ah[i+1]), y1 = Yf[(size_t)(i+1) * 16 + sm];
        float a2 = bf2f(ah[i+2]), y2 = Yf[(size_t)(i+2) * 16 + sm];
        float a3 = bf2f(ah[i+3]), y3 = Yf[(size_t)(i+3) * 16 + sm];
        for (i += 4; i + 4 <= iend; i += 4) {
            float b0 = bf2f(ah[i]),   z0 = Yf[(size_t)i * 16 + sm];
            float b1 = bf2f(ah[i+1]), z1 = Yf[(size_t)(i+1) * 16 + sm];
            float b2 = bf2f(ah[i+2]), z2 = Yf[(size_t)(i+2) * 16 + sm];
            float b3 = bf2f(ah[i+3]), z3 = Yf[(size_t)(i+3) * 16 + sm];
            acc += a0 * y0 + a1 * y1 + a2 * y2 + a3 * y3;
            a0 = b0; a1 = b1; a2 = b2; a3 = b3;
            y0 = z0; y1 = z1; y2 = z2; y3 = z3;
        }
        acc += a0 * y0 + a1 * y1 + a2 * y2 + a3 * y3;
    }
    for (; i < end; i++)
        acc += bf2f(ah[i]) * Yf[(size_t)i * 16 + sm];
    Vih[(size_t)n * 64 + lane] = f2bf(acc);
}

__global__ __launch_bounds__(256) void k_agg0(const int* off, const int* src_c,
        const float* Yf, const ushort_t* aijh, const ushort_t* vh,
        ushort_t* cxm, ushort_t* Vih) {
    int wid  = blockIdx.x * 4 + (threadIdx.x >> 6);
    int lane = threadIdx.x & 63;
    if (wid < N_NODES)
        mi_wave(wid, lane, off, src_c, aijh, vh, cxm);
    else
        vi_wave(wid - N_NODES, lane, off, Yf, aijh, Vih);
}

__global__ __launch_bounds__(256) void k_agg1(const int* off, const int* src_c,
        const ushort_t* aijh, const ushort_t* vh, ushort_t* cxm) {
    int wid  = blockIdx.x * 4 + (threadIdx.x >> 6);
    int lane = threadIdx.x & 63;
    mi_wave(wid, lane, off, src_c, aijh, vh, cxm);
}

// ---------------- launch ----------------

extern "C" void kernel_launch(void* const* d_in, const int* in_sizes, int n_in,
                              void* d_out, int out_size, void* d_ws, size_t ws_size,
                              hipStream_t stream) {
    const int*   species = (const int*)  d_in[0];
    const float* dist    = (const float*)d_in[1];
    const float* swit    = (const float*)d_in[2];
    const int*   esrc    = (const int*)  d_in[3];
    const int*   edst    = (const int*)  d_in[4];
    const float* vec     = (const float*)d_in[5];
    const float* z_table = (const float*)d_in[6];
    const float* wsp     = (const float*)d_in[7];
    const float* pw1_0 = (const float*)d_in[8],  *pb1_0 = (const float*)d_in[9];
    const float* pw2_0 = (const float*)d_in[10], *pb2_0 = (const float*)d_in[11];
    const float* wq0 = (const float*)d_in[12], *wk0 = (const float*)d_in[13];
    const float* wv0 = (const float*)d_in[14], *uw0 = (const float*)d_in[15];
    const float* ub0 = (const float*)d_in[16];
    const float* pw1_1 = (const float*)d_in[17], *pb1_1 = (const float*)d_in[18];
    const float* pw2_1 = (const float*)d_in[19], *pb2_1 = (const float*)d_in[20];
    const float* wq1 = (const float*)d_in[21], *wk1 = (const float*)d_in[22];
    const float* wv1 = (const float*)d_in[23], *uw1 = (const float*)d_in[24];
    const float* ub1 = (const float*)d_in[25];
    float* out = (float*)d_out;

    char* p = (char*)d_ws;
    auto alloc = [&](size_t bytes) -> char* {
        char* r = p;
        p += (bytes + 255) & ~(size_t)255;
        return r;
    };
    int* deg    = (int*)alloc((size_t)N_NODES * 4);
    int* off    = (int*)alloc((size_t)(N_NODES + 1) * 4);
    int* rank   = (int*)alloc((size_t)N_EDGES * 4);
    int* perm   = (int*)alloc((size_t)N_EDGES * 4);
    uint4* pk   = (uint4*)alloc((size_t)N_EDGES * 32);
    int*   src_c  = (int*)  alloc((size_t)N_EDGES * 4);
    int*   dst_c  = (int*)  alloc((size_t)N_EDGES * 4);
    float* dist_c = (float*)alloc((size_t)N_EDGES * 4);
    float* sc_c   = (float*)alloc((size_t)N_EDGES * 4);
    float* Yf     = (float*)alloc((size_t)N_EDGES * 16 * 4);
    float* xiA  = (float*)alloc((size_t)N_NODES * DIM * 4);
    float* xiB  = (float*)alloc((size_t)N_NODES * DIM * 4);
    ushort_t* xib  = (ushort_t*)alloc((size_t)N_PAD * KQ * 2);
    ushort_t* cxm  = (ushort_t*)alloc((size_t)N_PAD * UI_W * 2);
    ushort_t* qh   = (ushort_t*)alloc((size_t)N_NODES * QK_W * 2);
    ushort_t* kh   = (ushort_t*)alloc((size_t)N_NODES * QK_W * 2);
    ushort_t* vh   = (ushort_t*)alloc((size_t)N_NODES * DIM * 2);
    ushort_t* Wtq0 = (ushort_t*)alloc((size_t)832 * KQ * 2);
    ushort_t* Wtq1 = (ushort_t*)alloc((size_t)832 * KQ * 2);
    ushort_t* Wtu0 = (ushort_t*)alloc((size_t)192 * UI_W * 2);
    ushort_t* Wtu1 = (ushort_t*)alloc((size_t)192 * UI_W * 2);
    ushort_t* w1T0 = (ushort_t*)alloc((size_t)32 * 32 * 2);
    ushort_t* w2T0 = (ushort_t*)alloc((size_t)16 * 32 * 2);
    ushort_t* w1T1 = (ushort_t*)alloc((size_t)32 * 32 * 2);
    ushort_t* w2T1 = (ushort_t*)alloc((size_t)16 * 32 * 2);
    ushort_t* Vih  = (ushort_t*)alloc((size_t)N_NODES * 64 * 2);
    ushort_t* aijh = (ushort_t*)alloc((size_t)N_EDGES * NH * 2);

    const int NB_E  = (N_EDGES + 255) / 256;   // 1250
    const int NB_F  = N_EDGES / 64;            // 5000 (fused edge kernel)
    const dim3 GRID_QKV(13, 157);

    hipMemsetAsync(deg, 0, (size_t)N_NODES * 4, stream);
    k_pre<<<3663, 256, 0, stream>>>(edst, esrc, dist, swit, vec, deg, rank, pk,
                                    wq0, wk0, wv0, Wtq0, wq1, wk1, wv1, Wtq1,
                                    uw0, Wtu0, uw1, Wtu1,
                                    pw1_0, pw2_0, w1T0, w2T0,
                                    pw1_1, pw2_1, w1T1, w2T1,
                                    species, z_table, wsp, xiA, xib, cxm);
    k_scan<<<1, 1024, 0, stream>>>(deg, off);
    k_perm<<<NB_E, 256, 0, stream>>>(edst, rank, off, perm);
    k_build<<<NB_E, 256, 0, stream>>>(perm, pk, src_c, dst_c, dist_c, sc_c, Yf);

    // layer 0
    k_gemmq<<<GRID_QKV, 256, 0, stream>>>(xib, Wtq0, qh, kh, vh);
    k_edge<true><<<NB_F, 256, 0, stream>>>(dist_c, sc_c, src_c, dst_c, Yf, Vih,
                                           qh, kh, w1T0, pb1_0, w2T0, pb2_0, aijh);
    k_agg0<<<5000, 256, 0, stream>>>(off, src_c, Yf, aijh, vh, cxm, Vih);
    k_updln<<<157, 256, 0, stream>>>(cxm, Wtu0, xiA, ub0, xiB, xib, cxm);

    // layer 1
    k_gemmq<<<GRID_QKV, 256, 0, stream>>>(xib, Wtq1, qh, kh, vh);
    k_edge<false><<<NB_F, 256, 0, stream>>>(dist_c, sc_c, src_c, dst_c, Yf, Vih,
                                            qh, kh, w1T1, pb1_1, w2T1, pb2_1, aijh);
    k_agg1<<<2500, 256, 0, stream>>>(off, src_c, aijh, vh, cxm);
    k_updln<<<157, 256, 0, stream>>>(cxm, Wtu1, xiB, ub1, out, xib, cxm);
}

// Round 9
// 367.971 us; speedup vs baseline: 1.0556x; 1.0556x over previous
//
#include <hip/hip_runtime.h>
#include <hip/hip_bf16.h>
#include <math.h>

#define N_NODES 10000
#define N_PAD   10048       // 157 * 64
#define N_EDGES 320000
#define DIM     176
#define ATT     16
#define SH_HEADS 16
#define THH     4
#define NH      20          // SH_HEADS + TH
#define VD      11          // DIM / SH_HEADS
#define ZDIM    16
#define RDIM    16
#define QK_W    (NH*ATT)    // 320
#define QKV_W   816         // 320+320+176
#define UI_W    (2*DIM)     // 352
#define KQ      192         // padded K for qkv gemm
#define SIGINV  3.5714285714285716f   // (RDIM-1)/(CUT-RSTART)
#define RSTEP   0.28f                 // (CUT-RSTART)/(RDIM-1)

typedef unsigned short ushort_t;
typedef __attribute__((ext_vector_type(8))) short bf16x8;
typedef __attribute__((ext_vector_type(4))) float f32x4;

// ---------------- helpers ----------------

__device__ __forceinline__ ushort_t f2bf(float f) {
    __hip_bfloat16 b = __float2bfloat16(f);
    return *(ushort_t*)&b;
}

__device__ __forceinline__ float bf2f(ushort_t u) {
    return __uint_as_float(((unsigned)u) << 16);
}

__device__ __forceinline__ void sph16(float x, float y, float z, float* Y) {
    const float s3  = 1.7320508075688772f;
    const float s15 = 3.872983346207417f;
    const float c1  = 0.7905694150420949f;
    const float c2  = 0.6123724356957945f;
    float x2 = x*x, y2 = y*y, z2 = z*z;
    Y[0]  = 1.0f;
    Y[1]  = x;
    Y[2]  = y;
    Y[3]  = z;
    Y[4]  = s3 * x * y;
    Y[5]  = s3 * y * z;
    Y[6]  = 0.5f * (3.0f * z2 - 1.0f);
    Y[7]  = s3 * x * z;
    Y[8]  = 0.5f * s3 * (x2 - y2);
    Y[9]  = c1 * y * (3.0f * x2 - y2);
    Y[10] = s15 * x * y * z;
    Y[11] = c2 * y * (5.0f * z2 - 1.0f);
    Y[12] = 0.5f * z * (5.0f * z2 - 3.0f);
    Y[13] = c2 * x * (5.0f * z2 - 1.0f);
    Y[14] = 0.5f * s15 * z * (x2 - y2);
    Y[15] = c1 * x * (x2 - 3.0f * y2);
}

__device__ __forceinline__ void unpack8(const uint4 u, float* f) {
    f[0] = __uint_as_float(u.x << 16);
    f[1] = __uint_as_float(u.x & 0xffff0000u);
    f[2] = __uint_as_float(u.y << 16);
    f[3] = __uint_as_float(u.y & 0xffff0000u);
    f[4] = __uint_as_float(u.z << 16);
    f[5] = __uint_as_float(u.z & 0xffff0000u);
    f[6] = __uint_as_float(u.w << 16);
    f[7] = __uint_as_float(u.w & 0xffff0000u);
}

// ---------------- merged prologue: deg+pack | weight prep | node embed ------

__device__ __forceinline__ void deg_body(int bid, int tid,
        const int* __restrict__ edst, const int* __restrict__ esrc,
        const float* __restrict__ dist, const float* __restrict__ swit,
        const float* __restrict__ vec, int* deg, int* rank, uint4* pk) {
    int e = bid * 256 + tid;
    if (e >= N_EDGES) return;
    int t_ = edst[e];
    rank[e] = atomicAdd(&deg[t_], 1);
    uint4 a, b;
    a.x = (unsigned)esrc[e];
    a.y = (unsigned)t_;
    a.z = __float_as_uint(dist[e]);
    a.w = __float_as_uint(swit[e]);
    b.x = __float_as_uint(vec[(size_t)e*3 + 0]);
    b.y = __float_as_uint(vec[(size_t)e*3 + 1]);
    b.z = __float_as_uint(vec[(size_t)e*3 + 2]);
    b.w = 0u;
    pk[(size_t)e*2 + 0] = a;
    pk[(size_t)e*2 + 1] = b;
}

__device__ __forceinline__ void prep_qkv_body(int bid, int tid, const float* wq,
        const float* wk, const float* wv, ushort_t* Wtq) {
    int id = bid * 256 + tid;
    if (id >= 832 * KQ) return;
    int n = id / KQ, k = id - (id / KQ) * KQ;
    float v = 0.0f;
    if (k < DIM && n < QKV_W)
        v = (n < 320) ? wq[k * 320 + n] : (n < 640) ? wk[k * 320 + (n - 320)]
                                                    : wv[k * DIM + (n - 640)];
    Wtq[id] = f2bf(v);
}

__device__ __forceinline__ void prep_upd_body(int bid, int tid, const float* uw, ushort_t* Wtu) {
    int id = bid * 256 + tid;
    if (id >= 192 * UI_W) return;
    int n = id / UI_W, k = id - (id / UI_W) * UI_W;
    float v = (n < DIM) ? uw[k * DIM + n] : 0.0f;
    Wtu[id] = f2bf(v);
}

__device__ __forceinline__ void prep_mlp_body(int bid, int tid, const float* pw1,
        const float* pw2, ushort_t* w1T, ushort_t* w2T, int K1) {
    int id = bid * 256 + tid;
    if (id < 1024) {
        int n = id >> 5, k = id & 31;
        w1T[n * 32 + k] = (k < K1) ? f2bf(pw1[k * 32 + n]) : 0;
    } else if (id < 1536) {
        int id2 = id - 1024;
        int n = id2 >> 5, k = id2 & 31;
        w2T[n * 32 + k] = f2bf(pw2[k * 16 + n]);
    }
}

struct InitSmem {
    float zs[16 * ZDIM];
    float yt[16 * DIM];
    float red[256];
    float mus[16], rstds[16];
};

__device__ void init_body(int bid, int tid, InitSmem& sm,
        const int* species, const float* z_table, const float* wsp,
        float* xi, ushort_t* xib, ushort_t* cxm) {
    int base = bid * 16;
    { int n = tid >> 4, kk = tid & 15;
      sm.zs[tid] = z_table[species[base + n] * ZDIM + kk]; }
    __syncthreads();
    int c = tid;
    if (c < DIM) {
        float acc[16];
        #pragma unroll
        for (int n = 0; n < 16; n++) acc[n] = 0.0f;
        for (int kk = 0; kk < ZDIM; kk++) {
            float w = wsp[kk * DIM + c];
            #pragma unroll
            for (int n = 0; n < 16; n++) acc[n] += sm.zs[n * ZDIM + kk] * w;
        }
        #pragma unroll
        for (int n = 0; n < 16; n++) sm.yt[n * DIM + c] = acc[n];
    }
    __syncthreads();
    { int n2 = tid >> 4, j = tid & 15;
      float s = 0.0f;
      for (int c2 = j; c2 < DIM; c2 += 16) s += sm.yt[n2 * DIM + c2];
      sm.red[tid] = s; }
    __syncthreads();
    if (tid < 16) { float s = 0; for (int j = 0; j < 16; j++) s += sm.red[tid * 16 + j]; sm.mus[tid] = s / (float)DIM; }
    __syncthreads();
    { int n2 = tid >> 4, j = tid & 15;
      float mu = sm.mus[n2], s = 0.0f;
      for (int c2 = j; c2 < DIM; c2 += 16) { float d = sm.yt[n2 * DIM + c2] - mu; s += d * d; }
      sm.red[tid] = s; }
    __syncthreads();
    if (tid < 16) { float s = 0; for (int j = 0; j < 16; j++) s += sm.red[tid * 16 + j]; sm.rstds[tid] = rsqrtf(s / (float)DIM + 1e-6f); }
    __syncthreads();
    if (c < DIM) {
        #pragma unroll
        for (int n = 0; n < 16; n++) {
            float val = (sm.yt[n * DIM + c] - sm.mus[n]) * sm.rstds[n];
            xi[(size_t)(base + n) * DIM + c] = val;
            ushort_t bv = f2bf(val);
            xib[(size_t)(base + n) * KQ + c]   = bv;
            cxm[(size_t)(base + n) * UI_W + c] = bv;
        }
    } else if (c < KQ) {
        #pragma unroll
        for (int n = 0; n < 16; n++) xib[(size_t)(base + n) * KQ + c] = 0;
    }
}

// grid = 1250 (deg) + 1788 (prep) + 625 (node init) = 3663
__global__ __launch_bounds__(256) void k_pre(
        const int* edst, const int* esrc, const float* dist, const float* swit,
        const float* vec, int* deg, int* rank, uint4* pk,
        const float* wq0, const float* wk0, const float* wv0, ushort_t* Wtq0,
        const float* wq1, const float* wk1, const float* wv1, ushort_t* Wtq1,
        const float* uw0, ushort_t* Wtu0, const float* uw1, ushort_t* Wtu1,
        const float* pw1_0, const float* pw2_0, ushort_t* w1T0, ushort_t* w2T0,
        const float* pw1_1, const float* pw2_1, ushort_t* w1T1, ushort_t* w2T1,
        const int* species, const float* z_table, const float* wsp,
        float* xi, ushort_t* xib, ushort_t* cxm) {
    __shared__ InitSmem sm;
    int bid = blockIdx.x, tid = threadIdx.x;
    if (bid < 1250)       deg_body(bid, tid, edst, esrc, dist, swit, vec, deg, rank, pk);
    else if (bid < 1874)  prep_qkv_body(bid - 1250, tid, wq0, wk0, wv0, Wtq0);
    else if (bid < 2498)  prep_qkv_body(bid - 1874, tid, wq1, wk1, wv1, Wtq1);
    else if (bid < 2762)  prep_upd_body(bid - 2498, tid, uw0, Wtu0);
    else if (bid < 3026)  prep_upd_body(bid - 2762, tid, uw1, Wtu1);
    else if (bid < 3032)  prep_mlp_body(bid - 3026, tid, pw1_0, pw2_0, w1T0, w2T0, 16);
    else if (bid < 3038)  prep_mlp_body(bid - 3032, tid, pw1_1, pw2_1, w1T1, w2T1, 32);
    else                  init_body(bid - 3038, tid, sm, species, z_table, wsp, xi, xib, cxm);
}

// ---------------- single-block scan (deg -> off) ----------------

__global__ __launch_bounds__(1024) void k_scan(const int* __restrict__ deg, int* off) {
    __shared__ int sd[1024];
    int tid = threadIdx.x;
    int base = tid * 10;
    int v[10];
    int s = 0;
    #pragma unroll
    for (int j = 0; j < 10; j++) {
        int gi = base + j;
        v[j] = (gi < N_NODES) ? deg[gi] : 0;
        s += v[j];
    }
    sd[tid] = s;
    __syncthreads();
    for (int st = 1; st < 1024; st <<= 1) {
        int add = (tid >= st) ? sd[tid - st] : 0;
        __syncthreads();
        sd[tid] += add;
        __syncthreads();
    }
    int run = (tid > 0) ? sd[tid - 1] : 0;
    #pragma unroll
    for (int j = 0; j < 10; j++) {
        run += v[j];
        int gi = base + j;
        if (gi < N_NODES) off[gi + 1] = run;
    }
    if (tid == 0) off[0] = 0;
}

// scatter ONLY the 4-byte permutation index (CSR slot -> original edge)
__global__ __launch_bounds__(256) void k_perm(const int* edst, const int* rank,
                                              const int* off, int* perm) {
    int e = blockIdx.x * 256 + threadIdx.x;
    if (e >= N_EDGES) return;
    perm[off[edst[e]] + rank[e]] = e;
}

// thread = CSR slot: ONE random aligned 32 B read, fully coalesced writes
__global__ __launch_bounds__(256) void k_build(const int* __restrict__ perm,
        const uint4* __restrict__ pk,
        int* src_c, int* dst_c, float* dist_c, float* sc_c, float* Yf) {
    int p = blockIdx.x * 256 + threadIdx.x;
    if (p >= N_EDGES) return;
    int e  = perm[p];
    uint4 a = pk[(size_t)e*2 + 0];
    uint4 b = pk[(size_t)e*2 + 1];
    int s  = (int)a.x;
    int t_ = (int)a.y;
    float d  = __uint_as_float(a.z);
    float sw = __uint_as_float(a.w);
    float inv = 1.0f / d;
    float vx = __uint_as_float(b.x) * inv;
    float vy = __uint_as_float(b.y) * inv;
    float vz = __uint_as_float(b.z) * inv;
    src_c[p]  = s;
    dst_c[p]  = t_;
    dist_c[p] = d;
    sc_c[p]   = sw * 0.25f;               // switch / sqrt(ATT)
    float Y[16];
    sph16(vx, vy, vz, Y);
    #pragma unroll
    for (int m = 0; m < 16; m += 4)
        *(float4*)&Yf[(size_t)p * 16 + m] = make_float4(Y[m], Y[m+1], Y[m+2], Y[m+3]);
}

// ---------------- MFMA GEMM (QKV, K=192, single-stage full-K tiles) --------

__global__ __launch_bounds__(256) void k_gemmq(const ushort_t* __restrict__ A,
                                               const ushort_t* __restrict__ Bt,
                                               ushort_t* __restrict__ qh,
                                               ushort_t* __restrict__ kh,
                                               ushort_t* __restrict__ vh) {
    __shared__ ushort_t As[64 * 200];
    __shared__ ushort_t Bs[64 * 200];
    int tid  = threadIdx.x;
    int m0   = blockIdx.y * 64, n0 = blockIdx.x * 64;
    int w    = tid >> 6, lane = tid & 63, quad = lane >> 4, c16 = lane & 15;
    #pragma unroll
    for (int it = 0; it < 6; it++) {
        int seg = it * 256 + tid;
        int r = seg / 24, cs = seg - (seg / 24) * 24;
        *(uint4*)&As[r * 200 + cs * 8] =
            *(const uint4*)&A[(size_t)(m0 + r) * KQ + cs * 8];
        *(uint4*)&Bs[r * 200 + cs * 8] =
            *(const uint4*)&Bt[(size_t)(n0 + r) * KQ + cs * 8];
    }
    __syncthreads();
    f32x4 acc[4] = {};
    #pragma unroll
    for (int kc = 0; kc < 6; kc++) {
        bf16x8 a = *(const bf16x8*)&As[(w * 16 + c16) * 200 + kc * 32 + quad * 8];
        #pragma unroll
        for (int t = 0; t < 4; t++) {
            bf16x8 b = *(const bf16x8*)&Bs[(t * 16 + c16) * 200 + kc * 32 + quad * 8];
            acc[t] = __builtin_amdgcn_mfma_f32_16x16x32_bf16(a, b, acc[t], 0, 0, 0);
        }
    }
    #pragma unroll
    for (int t = 0; t < 4; t++) {
        #pragma unroll
        for (int r = 0; r < 4; r++) {
            int row = m0 + w * 16 + quad * 4 + r;
            int col = n0 + t * 16 + c16;
            if (row < N_NODES && col < QKV_W) {
                ushort_t bv = f2bf(acc[t][r]);
                if (col < 320)      qh[(size_t)row * QK_W + col] = bv;
                else if (col < 640) kh[(size_t)row * QK_W + (col - 320)] = bv;
                else                vh[(size_t)row * DIM  + (col - 640)] = bv;
            }
        }
    }
}

// ---------------- MFMA GEMM (UPD, K=352, two-stage full-K tiles) ----------
// K split 192+160 staged in the same 51.2 KB LDS: 3 barriers instead of 22.

__global__ __launch_bounds__(256) void k_gemmu(const ushort_t* __restrict__ A,
                                               const ushort_t* __restrict__ Bt,
                                               float* __restrict__ Cv) {
    __shared__ ushort_t As[64 * 200];
    __shared__ ushort_t Bs[64 * 200];
    int tid  = threadIdx.x;
    int m0   = blockIdx.y * 64, n0 = blockIdx.x * 64;
    int w    = tid >> 6, lane = tid & 63, quad = lane >> 4, c16 = lane & 15;
    f32x4 acc[4] = {};
    // ---- stage 1: K = 0..192 (24 uint4/row) ----
    #pragma unroll
    for (int it = 0; it < 6; it++) {
        int seg = it * 256 + tid;
        int r = seg / 24, cs = seg - (seg / 24) * 24;
        *(uint4*)&As[r * 200 + cs * 8] =
            *(const uint4*)&A[(size_t)(m0 + r) * UI_W + cs * 8];
        *(uint4*)&Bs[r * 200 + cs * 8] =
            *(const uint4*)&Bt[(size_t)(n0 + r) * UI_W + cs * 8];
    }
    __syncthreads();
    #pragma unroll
    for (int kc = 0; kc < 6; kc++) {
        bf16x8 a = *(const bf16x8*)&As[(w * 16 + c16) * 200 + kc * 32 + quad * 8];
        #pragma unroll
        for (int t = 0; t < 4; t++) {
            bf16x8 b = *(const bf16x8*)&Bs[(t * 16 + c16) * 200 + kc * 32 + quad * 8];
            acc[t] = __builtin_amdgcn_mfma_f32_16x16x32_bf16(a, b, acc[t], 0, 0, 0);
        }
    }
    __syncthreads();
    // ---- stage 2: K = 192..352 (20 uint4/row) ----
    #pragma unroll
    for (int it = 0; it < 5; it++) {
        int seg = it * 256 + tid;
        int r = seg / 20, cs = seg - (seg / 20) * 20;
        *(uint4*)&As[r * 200 + cs * 8] =
            *(const uint4*)&A[(size_t)(m0 + r) * UI_W + 192 + cs * 8];
        *(uint4*)&Bs[r * 200 + cs * 8] =
            *(const uint4*)&Bt[(size_t)(n0 + r) * UI_W + 192 + cs * 8];
    }
    __syncthreads();
    #pragma unroll
    for (int kc = 0; kc < 5; kc++) {
        bf16x8 a = *(const bf16x8*)&As[(w * 16 + c16) * 200 + kc * 32 + quad * 8];
        #pragma unroll
        for (int t = 0; t < 4; t++) {
            bf16x8 b = *(const bf16x8*)&Bs[(t * 16 + c16) * 200 + kc * 32 + quad * 8];
            acc[t] = __builtin_amdgcn_mfma_f32_16x16x32_bf16(a, b, acc[t], 0, 0, 0);
        }
    }
    #pragma unroll
    for (int t = 0; t < 4; t++) {
        #pragma unroll
        for (int r = 0; r < 4; r++) {
            int row = m0 + w * 16 + quad * 4 + r;
            int col = n0 + t * 16 + c16;
            if (row < N_NODES && col < DIM)
                Cv[(size_t)row * DIM + col] = acc[t][r];
        }
    }
}

// ---------------- fused edge kernel ----------------

template<bool L0>
__global__ __launch_bounds__(256) void k_edge(const float* dist_c, const float* sc_c,
        const int* src_c, const int* dst_c, const float* Yf, const ushort_t* Vih,
        const ushort_t* qh, const ushort_t* kh,
        const ushort_t* w1T, const float* pb1, const ushort_t* w2T, const float* pb2,
        ushort_t* aijh) {
    __shared__ ushort_t urS[64 * 40];
    __shared__ ushort_t Ht[4][16 * 40];
    __shared__ float    wdS[64 * 17];
    __shared__ ushort_t aS[NH][64];
    int tid  = threadIdx.x;
    int w    = tid >> 6, lane = tid & 63, quad = lane >> 4, c16 = lane & 15;
    int eb   = blockIdx.x * 64;

    // aij-phase mapping (known at entry; only depends on src_c/dst_c)
    int le = tid >> 2, part = tid & 3;
    int ie = eb + le;
    int sE = src_c[ie], tE = dst_c[ie];

    if (!L0) {
        int e  = tid & 63, tp = tid >> 6;   // 4 threads/edge: tp = th component
        int i  = eb + e;
        float d = dist_c[i];
        ushort_t ur4[4];
        #pragma unroll
        for (int r0 = 0; r0 < 4; r0++) {
            int r = tp * 4 + r0;
            float cc = 0.8f + (float)r * RSTEP;
            float uu = (d - cc) * SIGINV;
            ur4[r0] = f2bf(__expf(-uu * uu));
        }
        *(uint2*)&urS[e * 40 + tp * 4] = *(uint2*)ur4;
        float Y[16];
        #pragma unroll
        for (int m = 0; m < 16; m += 4) {
            float4 y = *(const float4*)&Yf[(size_t)i * 16 + m];
            Y[m] = y.x; Y[m+1] = y.y; Y[m+2] = y.z; Y[m+3] = y.w;
        }
        int s = src_c[i], t_ = dst_c[i];
        const uint4* vd4 = (const uint4*)(Vih + (size_t)t_ * 64);
        const uint4* vs4 = (const uint4*)(Vih + (size_t)s  * 64);
        int th = tp;
        float fd[16], fs[16];
        unpack8(vd4[2*th],   fd);     unpack8(vd4[2*th+1], fd+8);
        unpack8(vs4[2*th],   fs);     unpack8(vs4[2*th+1], fs+8);
        float us0 = (fd[0] + fs[0]) * Y[0];
        float us1 = 0.0f, us2 = 0.0f, us3 = 0.0f;
        #pragma unroll
        for (int m = 1; m < 4; m++)  us1 += (fd[m] - fs[m]) * Y[m];
        #pragma unroll
        for (int m = 4; m < 9; m++)  us2 += (fd[m] + fs[m]) * Y[m];
        #pragma unroll
        for (int m = 9; m < 16; m++) us3 += (fd[m] - fs[m]) * Y[m];
        urS[e * 40 + 16 + 0 * 4 + th] = f2bf(us0);
        urS[e * 40 + 16 + 1 * 4 + th] = f2bf(us1);
        urS[e * 40 + 16 + 2 * 4 + th] = f2bf(us2);
        urS[e * 40 + 16 + 3 * 4 + th] = f2bf(us3);
        __syncthreads();
    }

    // ---- k prefetch: 160 B contiguous segment of k[src], 10 x uint4 ----
    uint4 kr[10];
    {
        const uint4* kseg = (const uint4*)(kh + (size_t)sE * QK_W) + part * 10;
        #pragma unroll
        for (int j = 0; j < 10; j++) kr[j] = kseg[j];
    }

    {
        int e0 = eb + w * 16;
        bf16x8 a1;
        if (L0) {
            float d = dist_c[e0 + c16];
            #pragma unroll
            for (int j = 0; j < 8; j++) {
                int r = quad * 8 + j;
                float v = 0.0f;
                if (r < 16) { float cc = 0.8f + (float)r * RSTEP; float uu = (d - cc) * SIGINV; v = __expf(-uu * uu); }
                a1[j] = (short)f2bf(v);
            }
        } else {
            a1 = *(const bf16x8*)&urS[(w * 16 + c16) * 40 + quad * 8];
        }
        bf16x8 b0 = *(const bf16x8*)&w1T[c16 * 32 + quad * 8];
        bf16x8 b1 = *(const bf16x8*)&w1T[(16 + c16) * 32 + quad * 8];
        f32x4 acc0 = {}, acc1 = {};
        acc0 = __builtin_amdgcn_mfma_f32_16x16x32_bf16(a1, b0, acc0, 0, 0, 0);
        acc1 = __builtin_amdgcn_mfma_f32_16x16x32_bf16(a1, b1, acc1, 0, 0, 0);
        float bb0 = pb1[c16], bb1 = pb1[c16 + 16];
        #pragma unroll
        for (int r = 0; r < 4; r++) {
            int er = quad * 4 + r;
            float h0 = acc0[r] + bb0; h0 = h0 / (1.0f + __expf(-h0));
            float h1 = acc1[r] + bb1; h1 = h1 / (1.0f + __expf(-h1));
            Ht[w][er * 40 + c16]      = f2bf(h0);
            Ht[w][er * 40 + 16 + c16] = f2bf(h1);
        }
        __syncthreads();
        bf16x8 a2 = *(const bf16x8*)&Ht[w][c16 * 40 + quad * 8];
        bf16x8 b2 = *(const bf16x8*)&w2T[c16 * 32 + quad * 8];
        f32x4 acc2 = {};
        acc2 = __builtin_amdgcn_mfma_f32_16x16x32_bf16(a2, b2, acc2, 0, 0, 0);
        float bb2 = pb2[c16];
        #pragma unroll
        for (int r = 0; r < 4; r++) {
            int er = quad * 4 + r;
            wdS[(w * 16 + er) * 17 + c16] = (acc2[r] + bb2) * sc_c[e0 + er];
        }
    }
    __syncthreads();

    {
        float wd[16];
        #pragma unroll
        for (int p = 0; p < 16; p++) wd[p] = wdS[le * 17 + p];
        const uint4* q4 = (const uint4*)(qh + (size_t)tE * QK_W) + part * 10;
        #pragma unroll
        for (int j = 0; j < 5; j++) {
            int h = part * 5 + j;
            float qa[8], qb[8], ka[8], kb[8];
            unpack8(q4[2*j],   qa); unpack8(q4[2*j+1], qb);
            unpack8(kr[2*j],   ka); unpack8(kr[2*j+1], kb);
            float acc = 0.0f;
            #pragma unroll
            for (int dd = 0; dd < 8; dd++) acc += qa[dd] * ka[dd] * wd[dd];
            #pragma unroll
            for (int dd = 0; dd < 8; dd++) acc += qb[dd] * kb[dd] * wd[8 + dd];
            aS[h][le] = f2bf(acc);
        }
    }
    __syncthreads();
    {
        const uint* aSw = (const uint*)aS;
        for (int idx = tid; idx < NH * 32; idx += 256) {
            int h = idx >> 5, w2 = idx & 31;
            *(uint*)(aijh + (size_t)h * N_EDGES + eb + w2 * 2) = aSw[h * 32 + w2];
        }
    }
}

// ---------------- aggregation: one wave per node for BOTH mi and Vi ----------

__device__ __forceinline__ void mi_step(int i, int c0, bool f1, bool f2,
        const int* src_c, const ushort_t* aA, const ushort_t* aB, const ushort_t* vh,
        float& acc0, float& acc1, float& acc2, float& acc3) {
    int s0 = src_c[i];
    uint2 v0 = *(const uint2*)(vh + (size_t)s0 * DIM + c0);
    float a00 = bf2f(aA[i]), a0B = bf2f(aB[i]);
    float g01 = f1 ? a0B : a00, g02 = f2 ? a0B : a00;
    acc0 += a00 * __uint_as_float(v0.x << 16);
    acc1 += g01 * __uint_as_float(v0.x & 0xffff0000u);
    acc2 += g02 * __uint_as_float(v0.y << 16);
    acc3 += a0B * __uint_as_float(v0.y & 0xffff0000u);
}

// software-pipelined: load chunk c+1 (srcs, v-rows, aij) while computing chunk c
__device__ __forceinline__ void mi_wave(int n, int lane, const int* off, const int* src_c,
        const ushort_t* aijh, const ushort_t* vh, ushort_t* cxm) {
    if (lane >= 44) return;
    int c0 = lane * 4;
    int hA = c0 / VD;
    int hB = (c0 + 3) / VD;
    bool f1 = ((c0 + 1) / VD) != hA;
    bool f2 = ((c0 + 2) / VD) != hA;
    const ushort_t* aA = aijh + (size_t)hA * N_EDGES;
    const ushort_t* aB = aijh + (size_t)hB * N_EDGES;
    int start = off[n], end = off[n + 1];
    float acc0 = 0, acc1 = 0, acc2 = 0, acc3 = 0;
    int cnt = end - start;
    int i = start;

#define MI_ACC(vv, av, bv) { \
    float aa = bf2f(av), ab = bf2f(bv); \
    float g1 = f1 ? ab : aa, g2 = f2 ? ab : aa; \
    acc0 += aa * __uint_as_float((vv).x << 16); \
    acc1 += g1 * __uint_as_float((vv).x & 0xffff0000u); \
    acc2 += g2 * __uint_as_float((vv).y << 16); \
    acc3 += ab * __uint_as_float((vv).y & 0xffff0000u); }

    if (cnt >= 4) {
        int iend = start + (cnt & ~3);
        int s0 = src_c[i], s1 = src_c[i+1], s2 = src_c[i+2], s3 = src_c[i+3];
        uint2 v0 = *(const uint2*)(vh + (size_t)s0 * DIM + c0);
        uint2 v1 = *(const uint2*)(vh + (size_t)s1 * DIM + c0);
        uint2 v2 = *(const uint2*)(vh + (size_t)s2 * DIM + c0);
        uint2 v3 = *(const uint2*)(vh + (size_t)s3 * DIM + c0);
        ushort_t pA0 = aA[i], pA1 = aA[i+1], pA2 = aA[i+2], pA3 = aA[i+3];
        ushort_t pB0 = aB[i], pB1 = aB[i+1], pB2 = aB[i+2], pB3 = aB[i+3];
        for (i += 4; i + 4 <= iend; i += 4) {
            int t0 = src_c[i], t1 = src_c[i+1], t2 = src_c[i+2], t3 = src_c[i+3];
            uint2 w0 = *(const uint2*)(vh + (size_t)t0 * DIM + c0);
            uint2 w1 = *(const uint2*)(vh + (size_t)t1 * DIM + c0);
            uint2 w2 = *(const uint2*)(vh + (size_t)t2 * DIM + c0);
            uint2 w3 = *(const uint2*)(vh + (size_t)t3 * DIM + c0);
            ushort_t qA0 = aA[i], qA1 = aA[i+1], qA2 = aA[i+2], qA3 = aA[i+3];
            ushort_t qB0 = aB[i], qB1 = aB[i+1], qB2 = aB[i+2], qB3 = aB[i+3];
            MI_ACC(v0, pA0, pB0); MI_ACC(v1, pA1, pB1);
            MI_ACC(v2, pA2, pB2); MI_ACC(v3, pA3, pB3);
            v0 = w0; v1 = w1; v2 = w2; v3 = w3;
            pA0 = qA0; pA1 = qA1; pA2 = qA2; pA3 = qA3;
            pB0 = qB0; pB1 = qB1; pB2 = qB2; pB3 = qB3;
        }
        MI_ACC(v0, pA0, pB0); MI_ACC(v1, pA1, pB1);
        MI_ACC(v2, pA2, pB2); MI_ACC(v3, pA3, pB3);
    }
    for (; i < end; i++)
        mi_step(i, c0, f1, f2, src_c, aA, aB, vh, acc0, acc1, acc2, acc3);
#undef MI_ACC
    ushort_t o[4] = {f2bf(acc0), f2bf(acc1), f2bf(acc2), f2bf(acc3)};
    *(uint2*)(cxm + (size_t)n * UI_W + DIM + c0) = *(uint2*)o;
}

// software-pipelined vi reduction
__device__ __forceinline__ void vi_wave(int n, int lane, const int* off,
        const float* Yf, const ushort_t* aijh, ushort_t* Vih) {
    int th = lane >> 4, sm = lane & 15;
    const ushort_t* ah = aijh + (size_t)(SH_HEADS + th) * N_EDGES;
    int start = off[n], end = off[n + 1];
    float acc = 0.0f;
    int cnt = end - start;
    int i = start;
    if (cnt >= 4) {
        int iend = start + (cnt & ~3);
        float a0 = bf2f(ah[i]),   y0 = Yf[(size_t)i * 16 + sm];
        float a1 = bf2f(ah[i+1]), y1 = Yf[(size_t)(i+1) * 16 + sm];
        float a2 = bf2f(ah[i+2]), y2 = Yf[(size_t)(i+2) * 16 + sm];
        float a3 = bf2f(ah[i+3]), y3 = Yf[(size_t)(i+3) * 16 + sm];
        for (i += 4; i + 4 <= iend; i += 4) {
            float b0 = bf2f(ah[i]),   z0 = Yf[(size_t)i * 16 + sm];
            float b1 = bf2f(ah[i+1]), z1 = Yf[(size_t)(i+1) * 16 + sm];
            float b2 = bf2f(ah[i+2]), z2 = Yf[(size_t)(i+2) * 16 + sm];
            float b3 = bf2f(ah[i+3]), z3 = Yf[(size_t)(i+3) * 16 + sm];
            acc += a0 * y0 + a1 * y1 + a2 * y2 + a3 * y3;
            a0 = b0; a1 = b1; a2 = b2; a3 = b3;
            y0 = z0; y1 = z1; y2 = z2; y3 = z3;
        }
        acc += a0 * y0 + a1 * y1 + a2 * y2 + a3 * y3;
    }
    for (; i < end; i++)
        acc += bf2f(ah[i]) * Yf[(size_t)i * 16 + sm];
    Vih[(size_t)n * 64 + lane] = f2bf(acc);
}

__global__ __launch_bounds__(256) void k_agg0(const int* off, const int* src_c,
        const float* Yf, const ushort_t* aijh, const ushort_t* vh,
        ushort_t* cxm, ushort_t* Vih) {
    int wid  = blockIdx.x * 4 + (threadIdx.x >> 6);
    int lane = threadIdx.x & 63;
    if (wid < N_NODES)
        mi_wave(wid, lane, off, src_c, aijh, vh, cxm);
    else
        vi_wave(wid - N_NODES, lane, off, Yf, aijh, Vih);
}

__global__ __launch_bounds__(256) void k_agg1(const int* off, const int* src_c,
        const ushort_t* aijh, const ushort_t* vh, ushort_t* cxm) {
    int wid  = blockIdx.x * 4 + (threadIdx.x >> 6);
    int lane = threadIdx.x & 63;
    mi_wave(wid, lane, off, src_c, aijh, vh, cxm);
}

// ---------------- LN epilogue ----------------

__global__ __launch_bounds__(256) void k_lnfinal(const float* yg, const float* xi,
        const float* ub, float* xo, ushort_t* xib, ushort_t* cxm) {
    __shared__ float yt[16 * DIM];
    __shared__ float red[256];
    __shared__ float mus[16], rstds[16];
    int base = blockIdx.x * 16;
    int tid  = threadIdx.x;
    for (int idx = tid; idx < 16 * DIM; idx += 256) {
        int n = idx / DIM, c = idx - n * DIM;
        yt[idx] = xi[(size_t)(base + n) * DIM + c]
                + yg[(size_t)(base + n) * DIM + c] + ub[c];
    }
    __syncthreads();
    { int n2 = tid >> 4, j = tid & 15;
      float s = 0.0f;
      for (int c2 = j; c2 < DIM; c2 += 16) s += yt[n2 * DIM + c2];
      red[tid] = s; }
    __syncthreads();
    if (tid < 16) { float s = 0; for (int j = 0; j < 16; j++) s += red[tid * 16 + j]; mus[tid] = s / (float)DIM; }
    __syncthreads();
    { int n2 = tid >> 4, j = tid & 15;
      float mu = mus[n2], s = 0.0f;
      for (int c2 = j; c2 < DIM; c2 += 16) { float d = yt[n2 * DIM + c2] - mu; s += d * d; }
      red[tid] = s; }
    __syncthreads();
    if (tid < 16) { float s = 0; for (int j = 0; j < 16; j++) s += red[tid * 16 + j]; rstds[tid] = rsqrtf(s / (float)DIM + 1e-6f); }
    __syncthreads();
    int c = tid;
    if (c < DIM) {
        #pragma unroll
        for (int n = 0; n < 16; n++) {
            float val = (yt[n * DIM + c] - mus[n]) * rstds[n];
            xo[(size_t)(base + n) * DIM + c] = val;
            ushort_t bv = f2bf(val);
            xib[(size_t)(base + n) * KQ + c]   = bv;
            cxm[(size_t)(base + n) * UI_W + c] = bv;
        }
    } else if (c < KQ) {
        #pragma unroll
        for (int n = 0; n < 16; n++) xib[(size_t)(base + n) * KQ + c] = 0;
    }
}

// ---------------- launch ----------------

extern "C" void kernel_launch(void* const* d_in, const int* in_sizes, int n_in,
                              void* d_out, int out_size, void* d_ws, size_t ws_size,
                              hipStream_t stream) {
    const int*   species = (const int*)  d_in[0];
    const float* dist    = (const float*)d_in[1];
    const float* swit    = (const float*)d_in[2];
    const int*   esrc    = (const int*)  d_in[3];
    const int*   edst    = (const int*)  d_in[4];
    const float* vec     = (const float*)d_in[5];
    const float* z_table = (const float*)d_in[6];
    const float* wsp     = (const float*)d_in[7];
    const float* pw1_0 = (const float*)d_in[8],  *pb1_0 = (const float*)d_in[9];
    const float* pw2_0 = (const float*)d_in[10], *pb2_0 = (const float*)d_in[11];
    const float* wq0 = (const float*)d_in[12], *wk0 = (const float*)d_in[13];
    const float* wv0 = (const float*)d_in[14], *uw0 = (const float*)d_in[15];
    const float* ub0 = (const float*)d_in[16];
    const float* pw1_1 = (const float*)d_in[17], *pb1_1 = (const float*)d_in[18];
    const float* pw2_1 = (const float*)d_in[19], *pb2_1 = (const float*)d_in[20];
    const float* wq1 = (const float*)d_in[21], *wk1 = (const float*)d_in[22];
    const float* wv1 = (const float*)d_in[23], *uw1 = (const float*)d_in[24];
    const float* ub1 = (const float*)d_in[25];
    float* out = (float*)d_out;

    char* p = (char*)d_ws;
    auto alloc = [&](size_t bytes) -> char* {
        char* r = p;
        p += (bytes + 255) & ~(size_t)255;
        return r;
    };
    int* deg    = (int*)alloc((size_t)N_NODES * 4);
    int* off    = (int*)alloc((size_t)(N_NODES + 1) * 4);
    int* rank   = (int*)alloc((size_t)N_EDGES * 4);
    int* perm   = (int*)alloc((size_t)N_EDGES * 4);
    uint4* pk   = (uint4*)alloc((size_t)N_EDGES * 32);
    int*   src_c  = (int*)  alloc((size_t)N_EDGES * 4);
    int*   dst_c  = (int*)  alloc((size_t)N_EDGES * 4);
    float* dist_c = (float*)alloc((size_t)N_EDGES * 4);
    float* sc_c   = (float*)alloc((size_t)N_EDGES * 4);
    float* Yf     = (float*)alloc((size_t)N_EDGES * 16 * 4);
    float* xiA  = (float*)alloc((size_t)N_NODES * DIM * 4);
    float* xiB  = (float*)alloc((size_t)N_NODES * DIM * 4);
    ushort_t* xib  = (ushort_t*)alloc((size_t)N_PAD * KQ * 2);
    ushort_t* cxm  = (ushort_t*)alloc((size_t)N_PAD * UI_W * 2);
    ushort_t* qh   = (ushort_t*)alloc((size_t)N_NODES * QK_W * 2);
    ushort_t* kh   = (ushort_t*)alloc((size_t)N_NODES * QK_W * 2);
    ushort_t* vh   = (ushort_t*)alloc((size_t)N_NODES * DIM * 2);
    float* ybuf    = (float*)alloc((size_t)N_NODES * DIM * 4);
    ushort_t* Wtq0 = (ushort_t*)alloc((size_t)832 * KQ * 2);
    ushort_t* Wtq1 = (ushort_t*)alloc((size_t)832 * KQ * 2);
    ushort_t* Wtu0 = (ushort_t*)alloc((size_t)192 * UI_W * 2);
    ushort_t* Wtu1 = (ushort_t*)alloc((size_t)192 * UI_W * 2);
    ushort_t* w1T0 = (ushort_t*)alloc((size_t)32 * 32 * 2);
    ushort_t* w2T0 = (ushort_t*)alloc((size_t)16 * 32 * 2);
    ushort_t* w1T1 = (ushort_t*)alloc((size_t)32 * 32 * 2);
    ushort_t* w2T1 = (ushort_t*)alloc((size_t)16 * 32 * 2);
    ushort_t* Vih  = (ushort_t*)alloc((size_t)N_NODES * 64 * 2);
    ushort_t* aijh = (ushort_t*)alloc((size_t)N_EDGES * NH * 2);

    const int NB_E  = (N_EDGES + 255) / 256;   // 1250
    const int NB_F  = N_EDGES / 64;            // 5000 (fused edge kernel)
    const int NB_T  = N_NODES / 16;            // 625
    const dim3 GRID_QKV(13, 157);
    const dim3 GRID_UPD(3, 157);

    hipMemsetAsync(deg, 0, (size_t)N_NODES * 4, stream);
    k_pre<<<3663, 256, 0, stream>>>(edst, esrc, dist, swit, vec, deg, rank, pk,
                                    wq0, wk0, wv0, Wtq0, wq1, wk1, wv1, Wtq1,
                                    uw0, Wtu0, uw1, Wtu1,
                                    pw1_0, pw2_0, w1T0, w2T0,
                                    pw1_1, pw2_1, w1T1, w2T1,
                                    species, z_table, wsp, xiA, xib, cxm);
    k_scan<<<1, 1024, 0, stream>>>(deg, off);
    k_perm<<<NB_E, 256, 0, stream>>>(edst, rank, off, perm);
    k_build<<<NB_E, 256, 0, stream>>>(perm, pk, src_c, dst_c, dist_c, sc_c, Yf);

    // layer 0
    k_gemmq<<<GRID_QKV, 256, 0, stream>>>(xib, Wtq0, qh, kh, vh);
    k_edge<true><<<NB_F, 256, 0, stream>>>(dist_c, sc_c, src_c, dst_c, Yf, Vih,
                                           qh, kh, w1T0, pb1_0, w2T0, pb2_0, aijh);
    k_agg0<<<5000, 256, 0, stream>>>(off, src_c, Yf, aijh, vh, cxm, Vih);
    k_gemmu<<<GRID_UPD, 256, 0, stream>>>(cxm, Wtu0, ybuf);
    k_lnfinal<<<NB_T, 256, 0, stream>>>(ybuf, xiA, ub0, xiB, xib, cxm);

    // layer 1
    k_gemmq<<<GRID_QKV, 256, 0, stream>>>(xib, Wtq1, qh, kh, vh);
    k_edge<false><<<NB_F, 256, 0, stream>>>(dist_c, sc_c, src_c, dst_c, Yf, Vih,
                                            qh, kh, w1T1, pb1_1, w2T1, pb2_1, aijh);
    k_agg1<<<2500, 256, 0, stream>>>(off, src_c, aijh, vh, cxm);
    k_gemmu<<<GRID_UPD, 256, 0, stream>>>(cxm, Wtu1, ybuf);
    k_lnfinal<<<NB_T, 256, 0, stream>>>(ybuf, xiB, ub1, out, xib, cxm);
}

// Round 10
// 356.939 us; speedup vs baseline: 1.0882x; 1.0309x over previous
//
#include <hip/hip_runtime.h>
#include <hip/hip_bf16.h>
#include <math.h>

#define N_NODES 10000
#define N_PAD   10048       // 157 * 64
#define N_EDGES 320000
#define DIM     176
#define ATT     16
#define SH_HEADS 16
#define THH     4
#define NH      20          // SH_HEADS + TH
#define VD      11          // DIM / SH_HEADS
#define ZDIM    16
#define RDIM    16
#define QK_W    (NH*ATT)    // 320
#define QKV_W   816         // 320+320+176
#define UI_W    (2*DIM)     // 352
#define KQ      192         // padded K for qkv gemm
#define SIGINV  3.5714285714285716f   // (RDIM-1)/(CUT-RSTART)
#define RSTEP   0.28f                 // (CUT-RSTART)/(RDIM-1)

typedef unsigned short ushort_t;
typedef __attribute__((ext_vector_type(8))) short bf16x8;
typedef __attribute__((ext_vector_type(4))) float f32x4;

// ---------------- helpers ----------------

__device__ __forceinline__ ushort_t f2bf(float f) {
    __hip_bfloat16 b = __float2bfloat16(f);
    return *(ushort_t*)&b;
}

__device__ __forceinline__ float bf2f(ushort_t u) {
    return __uint_as_float(((unsigned)u) << 16);
}

__device__ __forceinline__ void sph16(float x, float y, float z, float* Y) {
    const float s3  = 1.7320508075688772f;
    const float s15 = 3.872983346207417f;
    const float c1  = 0.7905694150420949f;
    const float c2  = 0.6123724356957945f;
    float x2 = x*x, y2 = y*y, z2 = z*z;
    Y[0]  = 1.0f;
    Y[1]  = x;
    Y[2]  = y;
    Y[3]  = z;
    Y[4]  = s3 * x * y;
    Y[5]  = s3 * y * z;
    Y[6]  = 0.5f * (3.0f * z2 - 1.0f);
    Y[7]  = s3 * x * z;
    Y[8]  = 0.5f * s3 * (x2 - y2);
    Y[9]  = c1 * y * (3.0f * x2 - y2);
    Y[10] = s15 * x * y * z;
    Y[11] = c2 * y * (5.0f * z2 - 1.0f);
    Y[12] = 0.5f * z * (5.0f * z2 - 3.0f);
    Y[13] = c2 * x * (5.0f * z2 - 1.0f);
    Y[14] = 0.5f * s15 * z * (x2 - y2);
    Y[15] = c1 * x * (x2 - 3.0f * y2);
}

__device__ __forceinline__ void unpack8(const uint4 u, float* f) {
    f[0] = __uint_as_float(u.x << 16);
    f[1] = __uint_as_float(u.x & 0xffff0000u);
    f[2] = __uint_as_float(u.y << 16);
    f[3] = __uint_as_float(u.y & 0xffff0000u);
    f[4] = __uint_as_float(u.z << 16);
    f[5] = __uint_as_float(u.z & 0xffff0000u);
    f[6] = __uint_as_float(u.w << 16);
    f[7] = __uint_as_float(u.w & 0xffff0000u);
}

// ---------------- merged prologue: deg+pack | weight prep | node embed ------

__device__ __forceinline__ void deg_body(int bid, int tid,
        const int* __restrict__ edst, const int* __restrict__ esrc,
        const float* __restrict__ dist, const float* __restrict__ swit,
        const float* __restrict__ vec, int* deg, int* rank, uint4* pk) {
    int e = bid * 256 + tid;
    if (e >= N_EDGES) return;
    int t_ = edst[e];
    rank[e] = atomicAdd(&deg[t_], 1);
    uint4 a, b;
    a.x = (unsigned)esrc[e];
    a.y = (unsigned)t_;
    a.z = __float_as_uint(dist[e]);
    a.w = __float_as_uint(swit[e]);
    b.x = __float_as_uint(vec[(size_t)e*3 + 0]);
    b.y = __float_as_uint(vec[(size_t)e*3 + 1]);
    b.z = __float_as_uint(vec[(size_t)e*3 + 2]);
    b.w = 0u;
    pk[(size_t)e*2 + 0] = a;
    pk[(size_t)e*2 + 1] = b;
}

__device__ __forceinline__ void prep_qkv_body(int bid, int tid, const float* wq,
        const float* wk, const float* wv, ushort_t* Wtq) {
    int id = bid * 256 + tid;
    if (id >= 832 * KQ) return;
    int n = id / KQ, k = id - (id / KQ) * KQ;
    float v = 0.0f;
    if (k < DIM && n < QKV_W)
        v = (n < 320) ? wq[k * 320 + n] : (n < 640) ? wk[k * 320 + (n - 320)]
                                                    : wv[k * DIM + (n - 640)];
    Wtq[id] = f2bf(v);
}

__device__ __forceinline__ void prep_upd_body(int bid, int tid, const float* uw, ushort_t* Wtu) {
    int id = bid * 256 + tid;
    if (id >= 192 * UI_W) return;
    int n = id / UI_W, k = id - (id / UI_W) * UI_W;
    float v = (n < DIM) ? uw[k * DIM + n] : 0.0f;
    Wtu[id] = f2bf(v);
}

__device__ __forceinline__ void prep_mlp_body(int bid, int tid, const float* pw1,
        const float* pw2, ushort_t* w1T, ushort_t* w2T, int K1) {
    int id = bid * 256 + tid;
    if (id < 1024) {
        int n = id >> 5, k = id & 31;
        w1T[n * 32 + k] = (k < K1) ? f2bf(pw1[k * 32 + n]) : 0;
    } else if (id < 1536) {
        int id2 = id - 1024;
        int n = id2 >> 5, k = id2 & 31;
        w2T[n * 32 + k] = f2bf(pw2[k * 16 + n]);
    }
}

struct InitSmem {
    float zs[16 * ZDIM];
    float yt[16 * DIM];
    float red[256];
    float mus[16], rstds[16];
};

__device__ void init_body(int bid, int tid, InitSmem& sm,
        const int* species, const float* z_table, const float* wsp,
        float* xi, ushort_t* xib, ushort_t* cxm) {
    int base = bid * 16;
    { int n = tid >> 4, kk = tid & 15;
      sm.zs[tid] = z_table[species[base + n] * ZDIM + kk]; }
    __syncthreads();
    int c = tid;
    if (c < DIM) {
        float acc[16];
        #pragma unroll
        for (int n = 0; n < 16; n++) acc[n] = 0.0f;
        for (int kk = 0; kk < ZDIM; kk++) {
            float w = wsp[kk * DIM + c];
            #pragma unroll
            for (int n = 0; n < 16; n++) acc[n] += sm.zs[n * ZDIM + kk] * w;
        }
        #pragma unroll
        for (int n = 0; n < 16; n++) sm.yt[n * DIM + c] = acc[n];
    }
    __syncthreads();
    { int n2 = tid >> 4, j = tid & 15;
      float s = 0.0f;
      for (int c2 = j; c2 < DIM; c2 += 16) s += sm.yt[n2 * DIM + c2];
      sm.red[tid] = s; }
    __syncthreads();
    if (tid < 16) { float s = 0; for (int j = 0; j < 16; j++) s += sm.red[tid * 16 + j]; sm.mus[tid] = s / (float)DIM; }
    __syncthreads();
    { int n2 = tid >> 4, j = tid & 15;
      float mu = sm.mus[n2], s = 0.0f;
      for (int c2 = j; c2 < DIM; c2 += 16) { float d = sm.yt[n2 * DIM + c2] - mu; s += d * d; }
      sm.red[tid] = s; }
    __syncthreads();
    if (tid < 16) { float s = 0; for (int j = 0; j < 16; j++) s += sm.red[tid * 16 + j]; sm.rstds[tid] = rsqrtf(s / (float)DIM + 1e-6f); }
    __syncthreads();
    if (c < DIM) {
        #pragma unroll
        for (int n = 0; n < 16; n++) {
            float val = (sm.yt[n * DIM + c] - sm.mus[n]) * sm.rstds[n];
            xi[(size_t)(base + n) * DIM + c] = val;
            ushort_t bv = f2bf(val);
            xib[(size_t)(base + n) * KQ + c]   = bv;
            cxm[(size_t)(base + n) * UI_W + c] = bv;
        }
    } else if (c < KQ) {
        #pragma unroll
        for (int n = 0; n < 16; n++) xib[(size_t)(base + n) * KQ + c] = 0;
    }
}

// grid = 1250 (deg) + 1788 (prep) + 625 (node init) = 3663
__global__ __launch_bounds__(256) void k_pre(
        const int* edst, const int* esrc, const float* dist, const float* swit,
        const float* vec, int* deg, int* rank, uint4* pk,
        const float* wq0, const float* wk0, const float* wv0, ushort_t* Wtq0,
        const float* wq1, const float* wk1, const float* wv1, ushort_t* Wtq1,
        const float* uw0, ushort_t* Wtu0, const float* uw1, ushort_t* Wtu1,
        const float* pw1_0, const float* pw2_0, ushort_t* w1T0, ushort_t* w2T0,
        const float* pw1_1, const float* pw2_1, ushort_t* w1T1, ushort_t* w2T1,
        const int* species, const float* z_table, const float* wsp,
        float* xi, ushort_t* xib, ushort_t* cxm) {
    __shared__ InitSmem sm;
    int bid = blockIdx.x, tid = threadIdx.x;
    if (bid < 1250)       deg_body(bid, tid, edst, esrc, dist, swit, vec, deg, rank, pk);
    else if (bid < 1874)  prep_qkv_body(bid - 1250, tid, wq0, wk0, wv0, Wtq0);
    else if (bid < 2498)  prep_qkv_body(bid - 1874, tid, wq1, wk1, wv1, Wtq1);
    else if (bid < 2762)  prep_upd_body(bid - 2498, tid, uw0, Wtu0);
    else if (bid < 3026)  prep_upd_body(bid - 2762, tid, uw1, Wtu1);
    else if (bid < 3032)  prep_mlp_body(bid - 3026, tid, pw1_0, pw2_0, w1T0, w2T0, 16);
    else if (bid < 3038)  prep_mlp_body(bid - 3032, tid, pw1_1, pw2_1, w1T1, w2T1, 32);
    else                  init_body(bid - 3038, tid, sm, species, z_table, wsp, xi, xib, cxm);
}

// ---------------- single-block scan (deg -> off) ----------------

__global__ __launch_bounds__(1024) void k_scan(const int* __restrict__ deg, int* off) {
    __shared__ int sd[1024];
    int tid = threadIdx.x;
    int base = tid * 10;
    int v[10];
    int s = 0;
    #pragma unroll
    for (int j = 0; j < 10; j++) {
        int gi = base + j;
        v[j] = (gi < N_NODES) ? deg[gi] : 0;
        s += v[j];
    }
    sd[tid] = s;
    __syncthreads();
    for (int st = 1; st < 1024; st <<= 1) {
        int add = (tid >= st) ? sd[tid - st] : 0;
        __syncthreads();
        sd[tid] += add;
        __syncthreads();
    }
    int run = (tid > 0) ? sd[tid - 1] : 0;
    #pragma unroll
    for (int j = 0; j < 10; j++) {
        run += v[j];
        int gi = base + j;
        if (gi < N_NODES) off[gi + 1] = run;
    }
    if (tid == 0) off[0] = 0;
}

// scatter ONLY the 4-byte permutation index (CSR slot -> original edge)
__global__ __launch_bounds__(256) void k_perm(const int* edst, const int* rank,
                                              const int* off, int* perm) {
    int e = blockIdx.x * 256 + threadIdx.x;
    if (e >= N_EDGES) return;
    perm[off[edst[e]] + rank[e]] = e;
}

// thread = CSR slot: ONE random aligned 32 B read, fully coalesced writes
// Yf stored as bf16 (16 x 2 B = 32 B per edge)
__global__ __launch_bounds__(256) void k_build(const int* __restrict__ perm,
        const uint4* __restrict__ pk,
        int* src_c, int* dst_c, float* dist_c, float* sc_c, ushort_t* Yfh) {
    int p = blockIdx.x * 256 + threadIdx.x;
    if (p >= N_EDGES) return;
    int e  = perm[p];
    uint4 a = pk[(size_t)e*2 + 0];
    uint4 b = pk[(size_t)e*2 + 1];
    int s  = (int)a.x;
    int t_ = (int)a.y;
    float d  = __uint_as_float(a.z);
    float sw = __uint_as_float(a.w);
    float inv = 1.0f / d;
    float vx = __uint_as_float(b.x) * inv;
    float vy = __uint_as_float(b.y) * inv;
    float vz = __uint_as_float(b.z) * inv;
    src_c[p]  = s;
    dst_c[p]  = t_;
    dist_c[p] = d;
    sc_c[p]   = sw * 0.25f;               // switch / sqrt(ATT)
    float Y[16];
    sph16(vx, vy, vz, Y);
    ushort_t yh[16];
    #pragma unroll
    for (int m = 0; m < 16; m++) yh[m] = f2bf(Y[m]);
    *(uint4*)&Yfh[(size_t)p * 16 + 0] = *(uint4*)&yh[0];
    *(uint4*)&Yfh[(size_t)p * 16 + 8] = *(uint4*)&yh[8];
}

// ---------------- MFMA GEMM (QKV, K=192, single-stage full-K tiles) --------

__global__ __launch_bounds__(256) void k_gemmq(const ushort_t* __restrict__ A,
                                               const ushort_t* __restrict__ Bt,
                                               ushort_t* __restrict__ qh,
                                               ushort_t* __restrict__ kh,
                                               ushort_t* __restrict__ vh) {
    __shared__ ushort_t As[64 * 200];
    __shared__ ushort_t Bs[64 * 200];
    int tid  = threadIdx.x;
    int m0   = blockIdx.y * 64, n0 = blockIdx.x * 64;
    int w    = tid >> 6, lane = tid & 63, quad = lane >> 4, c16 = lane & 15;
    #pragma unroll
    for (int it = 0; it < 6; it++) {
        int seg = it * 256 + tid;
        int r = seg / 24, cs = seg - (seg / 24) * 24;
        *(uint4*)&As[r * 200 + cs * 8] =
            *(const uint4*)&A[(size_t)(m0 + r) * KQ + cs * 8];
        *(uint4*)&Bs[r * 200 + cs * 8] =
            *(const uint4*)&Bt[(size_t)(n0 + r) * KQ + cs * 8];
    }
    __syncthreads();
    f32x4 acc[4] = {};
    #pragma unroll
    for (int kc = 0; kc < 6; kc++) {
        bf16x8 a = *(const bf16x8*)&As[(w * 16 + c16) * 200 + kc * 32 + quad * 8];
        #pragma unroll
        for (int t = 0; t < 4; t++) {
            bf16x8 b = *(const bf16x8*)&Bs[(t * 16 + c16) * 200 + kc * 32 + quad * 8];
            acc[t] = __builtin_amdgcn_mfma_f32_16x16x32_bf16(a, b, acc[t], 0, 0, 0);
        }
    }
    #pragma unroll
    for (int t = 0; t < 4; t++) {
        #pragma unroll
        for (int r = 0; r < 4; r++) {
            int row = m0 + w * 16 + quad * 4 + r;
            int col = n0 + t * 16 + c16;
            if (row < N_NODES && col < QKV_W) {
                ushort_t bv = f2bf(acc[t][r]);
                if (col < 320)      qh[(size_t)row * QK_W + col] = bv;
                else if (col < 640) kh[(size_t)row * QK_W + (col - 320)] = bv;
                else                vh[(size_t)row * DIM  + (col - 640)] = bv;
            }
        }
    }
}

// ---------------- MFMA GEMM (UPD, K=352, two-stage full-K tiles) ----------

__global__ __launch_bounds__(256) void k_gemmu(const ushort_t* __restrict__ A,
                                               const ushort_t* __restrict__ Bt,
                                               float* __restrict__ Cv) {
    __shared__ ushort_t As[64 * 200];
    __shared__ ushort_t Bs[64 * 200];
    int tid  = threadIdx.x;
    int m0   = blockIdx.y * 64, n0 = blockIdx.x * 64;
    int w    = tid >> 6, lane = tid & 63, quad = lane >> 4, c16 = lane & 15;
    f32x4 acc[4] = {};
    // ---- stage 1: K = 0..192 (24 uint4/row) ----
    #pragma unroll
    for (int it = 0; it < 6; it++) {
        int seg = it * 256 + tid;
        int r = seg / 24, cs = seg - (seg / 24) * 24;
        *(uint4*)&As[r * 200 + cs * 8] =
            *(const uint4*)&A[(size_t)(m0 + r) * UI_W + cs * 8];
        *(uint4*)&Bs[r * 200 + cs * 8] =
            *(const uint4*)&Bt[(size_t)(n0 + r) * UI_W + cs * 8];
    }
    __syncthreads();
    #pragma unroll
    for (int kc = 0; kc < 6; kc++) {
        bf16x8 a = *(const bf16x8*)&As[(w * 16 + c16) * 200 + kc * 32 + quad * 8];
        #pragma unroll
        for (int t = 0; t < 4; t++) {
            bf16x8 b = *(const bf16x8*)&Bs[(t * 16 + c16) * 200 + kc * 32 + quad * 8];
            acc[t] = __builtin_amdgcn_mfma_f32_16x16x32_bf16(a, b, acc[t], 0, 0, 0);
        }
    }
    __syncthreads();
    // ---- stage 2: K = 192..352 (20 uint4/row) ----
    #pragma unroll
    for (int it = 0; it < 5; it++) {
        int seg = it * 256 + tid;
        int r = seg / 20, cs = seg - (seg / 20) * 20;
        *(uint4*)&As[r * 200 + cs * 8] =
            *(const uint4*)&A[(size_t)(m0 + r) * UI_W + 192 + cs * 8];
        *(uint4*)&Bs[r * 200 + cs * 8] =
            *(const uint4*)&Bt[(size_t)(n0 + r) * UI_W + 192 + cs * 8];
    }
    __syncthreads();
    #pragma unroll
    for (int kc = 0; kc < 5; kc++) {
        bf16x8 a = *(const bf16x8*)&As[(w * 16 + c16) * 200 + kc * 32 + quad * 8];
        #pragma unroll
        for (int t = 0; t < 4; t++) {
            bf16x8 b = *(const bf16x8*)&Bs[(t * 16 + c16) * 200 + kc * 32 + quad * 8];
            acc[t] = __builtin_amdgcn_mfma_f32_16x16x32_bf16(a, b, acc[t], 0, 0, 0);
        }
    }
    #pragma unroll
    for (int t = 0; t < 4; t++) {
        #pragma unroll
        for (int r = 0; r < 4; r++) {
            int row = m0 + w * 16 + quad * 4 + r;
            int col = n0 + t * 16 + c16;
            if (row < N_NODES && col < DIM)
                Cv[(size_t)row * DIM + col] = acc[t][r];
        }
    }
}

// ---------------- fused edge kernel ----------------

template<bool L0>
__global__ __launch_bounds__(256) void k_edge(const float* dist_c, const float* sc_c,
        const int* src_c, const int* dst_c, const ushort_t* Yfh, const ushort_t* Vih,
        const ushort_t* qh, const ushort_t* kh,
        const ushort_t* w1T, const float* pb1, const ushort_t* w2T, const float* pb2,
        ushort_t* aijh) {
    __shared__ ushort_t urS[64 * 40];
    __shared__ ushort_t Ht[4][16 * 40];
    __shared__ float    wdS[64 * 17];
    __shared__ ushort_t aS[NH][64];
    int tid  = threadIdx.x;
    int w    = tid >> 6, lane = tid & 63, quad = lane >> 4, c16 = lane & 15;
    int eb   = blockIdx.x * 64;

    // aij-phase mapping (known at entry; only depends on src_c/dst_c)
    int le = tid >> 2, part = tid & 3;
    int ie = eb + le;
    int sE = src_c[ie], tE = dst_c[ie];

    if (!L0) {
        int e  = tid & 63, tp = tid >> 6;   // 4 threads/edge: tp = th component
        int i  = eb + e;
        float d = dist_c[i];
        ushort_t ur4[4];
        #pragma unroll
        for (int r0 = 0; r0 < 4; r0++) {
            int r = tp * 4 + r0;
            float cc = 0.8f + (float)r * RSTEP;
            float uu = (d - cc) * SIGINV;
            ur4[r0] = f2bf(__expf(-uu * uu));
        }
        *(uint2*)&urS[e * 40 + tp * 4] = *(uint2*)ur4;
        float Y[16];
        {
            uint4 y0 = *(const uint4*)&Yfh[(size_t)i * 16 + 0];
            uint4 y1 = *(const uint4*)&Yfh[(size_t)i * 16 + 8];
            unpack8(y0, Y);
            unpack8(y1, Y + 8);
        }
        int s = src_c[i], t_ = dst_c[i];
        const uint4* vd4 = (const uint4*)(Vih + (size_t)t_ * 64);
        const uint4* vs4 = (const uint4*)(Vih + (size_t)s  * 64);
        int th = tp;
        float fd[16], fs[16];
        unpack8(vd4[2*th],   fd);     unpack8(vd4[2*th+1], fd+8);
        unpack8(vs4[2*th],   fs);     unpack8(vs4[2*th+1], fs+8);
        float us0 = (fd[0] + fs[0]) * Y[0];
        float us1 = 0.0f, us2 = 0.0f, us3 = 0.0f;
        #pragma unroll
        for (int m = 1; m < 4; m++)  us1 += (fd[m] - fs[m]) * Y[m];
        #pragma unroll
        for (int m = 4; m < 9; m++)  us2 += (fd[m] + fs[m]) * Y[m];
        #pragma unroll
        for (int m = 9; m < 16; m++) us3 += (fd[m] - fs[m]) * Y[m];
        urS[e * 40 + 16 + 0 * 4 + th] = f2bf(us0);
        urS[e * 40 + 16 + 1 * 4 + th] = f2bf(us1);
        urS[e * 40 + 16 + 2 * 4 + th] = f2bf(us2);
        urS[e * 40 + 16 + 3 * 4 + th] = f2bf(us3);
        __syncthreads();
    }

    // ---- k prefetch: 160 B contiguous segment of k[src], 10 x uint4 ----
    uint4 kr[10];
    {
        const uint4* kseg = (const uint4*)(kh + (size_t)sE * QK_W) + part * 10;
        #pragma unroll
        for (int j = 0; j < 10; j++) kr[j] = kseg[j];
    }

    {
        int e0 = eb + w * 16;
        bf16x8 a1;
        if (L0) {
            float d = dist_c[e0 + c16];
            #pragma unroll
            for (int j = 0; j < 8; j++) {
                int r = quad * 8 + j;
                float v = 0.0f;
                if (r < 16) { float cc = 0.8f + (float)r * RSTEP; float uu = (d - cc) * SIGINV; v = __expf(-uu * uu); }
                a1[j] = (short)f2bf(v);
            }
        } else {
            a1 = *(const bf16x8*)&urS[(w * 16 + c16) * 40 + quad * 8];
        }
        bf16x8 b0 = *(const bf16x8*)&w1T[c16 * 32 + quad * 8];
        bf16x8 b1 = *(const bf16x8*)&w1T[(16 + c16) * 32 + quad * 8];
        f32x4 acc0 = {}, acc1 = {};
        acc0 = __builtin_amdgcn_mfma_f32_16x16x32_bf16(a1, b0, acc0, 0, 0, 0);
        acc1 = __builtin_amdgcn_mfma_f32_16x16x32_bf16(a1, b1, acc1, 0, 0, 0);
        float bb0 = pb1[c16], bb1 = pb1[c16 + 16];
        #pragma unroll
        for (int r = 0; r < 4; r++) {
            int er = quad * 4 + r;
            float h0 = acc0[r] + bb0; h0 = h0 / (1.0f + __expf(-h0));
            float h1 = acc1[r] + bb1; h1 = h1 / (1.0f + __expf(-h1));
            Ht[w][er * 40 + c16]      = f2bf(h0);
            Ht[w][er * 40 + 16 + c16] = f2bf(h1);
        }
        __syncthreads();
        bf16x8 a2 = *(const bf16x8*)&Ht[w][c16 * 40 + quad * 8];
        bf16x8 b2 = *(const bf16x8*)&w2T[c16 * 32 + quad * 8];
        f32x4 acc2 = {};
        acc2 = __builtin_amdgcn_mfma_f32_16x16x32_bf16(a2, b2, acc2, 0, 0, 0);
        float bb2 = pb2[c16];
        #pragma unroll
        for (int r = 0; r < 4; r++) {
            int er = quad * 4 + r;
            wdS[(w * 16 + er) * 17 + c16] = (acc2[r] + bb2) * sc_c[e0 + er];
        }
    }
    __syncthreads();

    {
        float wd[16];
        #pragma unroll
        for (int p = 0; p < 16; p++) wd[p] = wdS[le * 17 + p];
        const uint4* q4 = (const uint4*)(qh + (size_t)tE * QK_W) + part * 10;
        #pragma unroll
        for (int j = 0; j < 5; j++) {
            int h = part * 5 + j;
            float qa[8], qb[8], ka[8], kb[8];
            unpack8(q4[2*j],   qa); unpack8(q4[2*j+1], qb);
            unpack8(kr[2*j],   ka); unpack8(kr[2*j+1], kb);
            float acc = 0.0f;
            #pragma unroll
            for (int dd = 0; dd < 8; dd++) acc += qa[dd] * ka[dd] * wd[dd];
            #pragma unroll
            for (int dd = 0; dd < 8; dd++) acc += qb[dd] * kb[dd] * wd[8 + dd];
            aS[h][le] = f2bf(acc);
        }
    }
    __syncthreads();
    {
        const uint* aSw = (const uint*)aS;
        for (int idx = tid; idx < NH * 32; idx += 256) {
            int h = idx >> 5, w2 = idx & 31;
            *(uint*)(aijh + (size_t)h * N_EDGES + eb + w2 * 2) = aSw[h * 32 + w2];
        }
    }
}

// ---------------- aggregation: one wave per node for BOTH mi and Vi ----------

__device__ __forceinline__ void mi_step(int i, int c0, bool f1, bool f2,
        const int* src_c, const ushort_t* aA, const ushort_t* aB, const ushort_t* vh,
        float& acc0, float& acc1, float& acc2, float& acc3) {
    int s0 = src_c[i];
    uint2 v0 = *(const uint2*)(vh + (size_t)s0 * DIM + c0);
    float a00 = bf2f(aA[i]), a0B = bf2f(aB[i]);
    float g01 = f1 ? a0B : a00, g02 = f2 ? a0B : a00;
    acc0 += a00 * __uint_as_float(v0.x << 16);
    acc1 += g01 * __uint_as_float(v0.x & 0xffff0000u);
    acc2 += g02 * __uint_as_float(v0.y << 16);
    acc3 += a0B * __uint_as_float(v0.y & 0xffff0000u);
}

// software-pipelined: load chunk c+1 (srcs, v-rows, aij) while computing chunk c
__device__ __forceinline__ void mi_wave(int n, int lane, const int* off, const int* src_c,
        const ushort_t* aijh, const ushort_t* vh, ushort_t* cxm) {
    if (lane >= 44) return;
    int c0 = lane * 4;
    int hA = c0 / VD;
    int hB = (c0 + 3) / VD;
    bool f1 = ((c0 + 1) / VD) != hA;
    bool f2 = ((c0 + 2) / VD) != hA;
    const ushort_t* aA = aijh + (size_t)hA * N_EDGES;
    const ushort_t* aB = aijh + (size_t)hB * N_EDGES;
    int start = off[n], end = off[n + 1];
    float acc0 = 0, acc1 = 0, acc2 = 0, acc3 = 0;
    int cnt = end - start;
    int i = start;

#define MI_ACC(vv, av, bv) { \
    float aa = bf2f(av), ab = bf2f(bv); \
    float g1 = f1 ? ab : aa, g2 = f2 ? ab : aa; \
    acc0 += aa * __uint_as_float((vv).x << 16); \
    acc1 += g1 * __uint_as_float((vv).x & 0xffff0000u); \
    acc2 += g2 * __uint_as_float((vv).y << 16); \
    acc3 += ab * __uint_as_float((vv).y & 0xffff0000u); }

    if (cnt >= 4) {
        int iend = start + (cnt & ~3);
        int s0 = src_c[i], s1 = src_c[i+1], s2 = src_c[i+2], s3 = src_c[i+3];
        uint2 v0 = *(const uint2*)(vh + (size_t)s0 * DIM + c0);
        uint2 v1 = *(const uint2*)(vh + (size_t)s1 * DIM + c0);
        uint2 v2 = *(const uint2*)(vh + (size_t)s2 * DIM + c0);
        uint2 v3 = *(const uint2*)(vh + (size_t)s3 * DIM + c0);
        ushort_t pA0 = aA[i], pA1 = aA[i+1], pA2 = aA[i+2], pA3 = aA[i+3];
        ushort_t pB0 = aB[i], pB1 = aB[i+1], pB2 = aB[i+2], pB3 = aB[i+3];
        for (i += 4; i + 4 <= iend; i += 4) {
            int t0 = src_c[i], t1 = src_c[i+1], t2 = src_c[i+2], t3 = src_c[i+3];
            uint2 w0 = *(const uint2*)(vh + (size_t)t0 * DIM + c0);
            uint2 w1 = *(const uint2*)(vh + (size_t)t1 * DIM + c0);
            uint2 w2 = *(const uint2*)(vh + (size_t)t2 * DIM + c0);
            uint2 w3 = *(const uint2*)(vh + (size_t)t3 * DIM + c0);
            ushort_t qA0 = aA[i], qA1 = aA[i+1], qA2 = aA[i+2], qA3 = aA[i+3];
            ushort_t qB0 = aB[i], qB1 = aB[i+1], qB2 = aB[i+2], qB3 = aB[i+3];
            MI_ACC(v0, pA0, pB0); MI_ACC(v1, pA1, pB1);
            MI_ACC(v2, pA2, pB2); MI_ACC(v3, pA3, pB3);
            v0 = w0; v1 = w1; v2 = w2; v3 = w3;
            pA0 = qA0; pA1 = qA1; pA2 = qA2; pA3 = qA3;
            pB0 = qB0; pB1 = qB1; pB2 = qB2; pB3 = qB3;
        }
        MI_ACC(v0, pA0, pB0); MI_ACC(v1, pA1, pB1);
        MI_ACC(v2, pA2, pB2); MI_ACC(v3, pA3, pB3);
    }
    for (; i < end; i++)
        mi_step(i, c0, f1, f2, src_c, aA, aB, vh, acc0, acc1, acc2, acc3);
#undef MI_ACC
    ushort_t o[4] = {f2bf(acc0), f2bf(acc1), f2bf(acc2), f2bf(acc3)};
    *(uint2*)(cxm + (size_t)n * UI_W + DIM + c0) = *(uint2*)o;
}

// software-pipelined vi reduction (Yfh in bf16)
__device__ __forceinline__ void vi_wave(int n, int lane, const int* off,
        const ushort_t* Yfh, const ushort_t* aijh, ushort_t* Vih) {
    int th = lane >> 4, sm = lane & 15;
    const ushort_t* ah = aijh + (size_t)(SH_HEADS + th) * N_EDGES;
    int start = off[n], end = off[n + 1];
    float acc = 0.0f;
    int cnt = end - start;
    int i = start;
    if (cnt >= 4) {
        int iend = start + (cnt & ~3);
        float a0 = bf2f(ah[i]),   y0 = bf2f(Yfh[(size_t)i * 16 + sm]);
        float a1 = bf2f(ah[i+1]), y1 = bf2f(Yfh[(size_t)(i+1) * 16 + sm]);
        float a2 = bf2f(ah[i+2]), y2 = bf2f(Yfh[(size_t)(i+2) * 16 + sm]);
        float a3 = bf2f(ah[i+3]), y3 = bf2f(Yfh[(size_t)(i+3) * 16 + sm]);
        for (i += 4; i + 4 <= iend; i += 4) {
            float b0 = bf2f(ah[i]),   z0 = bf2f(Yfh[(size_t)i * 16 + sm]);
            float b1 = bf2f(ah[i+1]), z1 = bf2f(Yfh[(size_t)(i+1) * 16 + sm]);
            float b2 = bf2f(ah[i+2]), z2 = bf2f(Yfh[(size_t)(i+2) * 16 + sm]);
            float b3 = bf2f(ah[i+3]), z3 = bf2f(Yfh[(size_t)(i+3) * 16 + sm]);
            acc += a0 * y0 + a1 * y1 + a2 * y2 + a3 * y3;
            a0 = b0; a1 = b1; a2 = b2; a3 = b3;
            y0 = z0; y1 = z1; y2 = z2; y3 = z3;
        }
        acc += a0 * y0 + a1 * y1 + a2 * y2 + a3 * y3;
    }
    for (; i < end; i++)
        acc += bf2f(ah[i]) * bf2f(Yfh[(size_t)i * 16 + sm]);
    Vih[(size_t)n * 64 + lane] = f2bf(acc);
}

__global__ __launch_bounds__(256) void k_agg0(const int* off, const int* src_c,
        const ushort_t* Yfh, const ushort_t* aijh, const ushort_t* vh,
        ushort_t* cxm, ushort_t* Vih) {
    int wid  = blockIdx.x * 4 + (threadIdx.x >> 6);
    int lane = threadIdx.x & 63;
    if (wid < N_NODES)
        mi_wave(wid, lane, off, src_c, aijh, vh, cxm);
    else
        vi_wave(wid - N_NODES, lane, off, Yfh, aijh, Vih);
}

__global__ __launch_bounds__(256) void k_agg1(const int* off, const int* src_c,
        const ushort_t* aijh, const ushort_t* vh, ushort_t* cxm) {
    int wid  = blockIdx.x * 4 + (threadIdx.x >> 6);
    int lane = threadIdx.x & 63;
    mi_wave(wid, lane, off, src_c, aijh, vh, cxm);
}

// ---------------- LN epilogue ----------------

__global__ __launch_bounds__(256) void k_lnfinal(const float* yg, const float* xi,
        const float* ub, float* xo, ushort_t* xib, ushort_t* cxm) {
    __shared__ float yt[16 * DIM];
    __shared__ float red[256];
    __shared__ float mus[16], rstds[16];
    int base = blockIdx.x * 16;
    int tid  = threadIdx.x;
    for (int idx = tid; idx < 16 * DIM; idx += 256) {
        int n = idx / DIM, c = idx - n * DIM;
        yt[idx] = xi[(size_t)(base + n) * DIM + c]
                + yg[(size_t)(base + n) * DIM + c] + ub[c];
    }
    __syncthreads();
    { int n2 = tid >> 4, j = tid & 15;
      float s = 0.0f;
      for (int c2 = j; c2 < DIM; c2 += 16) s += yt[n2 * DIM + c2];
      red[tid] = s; }
    __syncthreads();
    if (tid < 16) { float s = 0; for (int j = 0; j < 16; j++) s += red[tid * 16 + j]; mus[tid] = s / (float)DIM; }
    __syncthreads();
    { int n2 = tid >> 4, j = tid & 15;
      float mu = mus[n2], s = 0.0f;
      for (int c2 = j; c2 < DIM; c2 += 16) { float d = yt[n2 * DIM + c2] - mu; s += d * d; }
      red[tid] = s; }
    __syncthreads();
    if (tid < 16) { float s = 0; for (int j = 0; j < 16; j++) s += red[tid * 16 + j]; rstds[tid] = rsqrtf(s / (float)DIM + 1e-6f); }
    __syncthreads();
    int c = tid;
    if (c < DIM) {
        #pragma unroll
        for (int n = 0; n < 16; n++) {
            float val = (yt[n * DIM + c] - mus[n]) * rstds[n];
            xo[(size_t)(base + n) * DIM + c] = val;
            ushort_t bv = f2bf(val);
            xib[(size_t)(base + n) * KQ + c]   = bv;
            cxm[(size_t)(base + n) * UI_W + c] = bv;
        }
    } else if (c < KQ) {
        #pragma unroll
        for (int n = 0; n < 16; n++) xib[(size_t)(base + n) * KQ + c] = 0;
    }
}

// ---------------- launch ----------------

extern "C" void kernel_launch(void* const* d_in, const int* in_sizes, int n_in,
                              void* d_out, int out_size, void* d_ws, size_t ws_size,
                              hipStream_t stream) {
    const int*   species = (const int*)  d_in[0];
    const float* dist    = (const float*)d_in[1];
    const float* swit    = (const float*)d_in[2];
    const int*   esrc    = (const int*)  d_in[3];
    const int*   edst    = (const int*)  d_in[4];
    const float* vec     = (const float*)d_in[5];
    const float* z_table = (const float*)d_in[6];
    const float* wsp     = (const float*)d_in[7];
    const float* pw1_0 = (const float*)d_in[8],  *pb1_0 = (const float*)d_in[9];
    const float* pw2_0 = (const float*)d_in[10], *pb2_0 = (const float*)d_in[11];
    const float* wq0 = (const float*)d_in[12], *wk0 = (const float*)d_in[13];
    const float* wv0 = (const float*)d_in[14], *uw0 = (const float*)d_in[15];
    const float* ub0 = (const float*)d_in[16];
    const float* pw1_1 = (const float*)d_in[17], *pb1_1 = (const float*)d_in[18];
    const float* pw2_1 = (const float*)d_in[19], *pb2_1 = (const float*)d_in[20];
    const float* wq1 = (const float*)d_in[21], *wk1 = (const float*)d_in[22];
    const float* wv1 = (const float*)d_in[23], *uw1 = (const float*)d_in[24];
    const float* ub1 = (const float*)d_in[25];
    float* out = (float*)d_out;

    char* p = (char*)d_ws;
    auto alloc = [&](size_t bytes) -> char* {
        char* r = p;
        p += (bytes + 255) & ~(size_t)255;
        return r;
    };
    int* deg    = (int*)alloc((size_t)N_NODES * 4);
    int* off    = (int*)alloc((size_t)(N_NODES + 1) * 4);
    int* rank   = (int*)alloc((size_t)N_EDGES * 4);
    int* perm   = (int*)alloc((size_t)N_EDGES * 4);
    uint4* pk   = (uint4*)alloc((size_t)N_EDGES * 32);
    int*   src_c  = (int*)  alloc((size_t)N_EDGES * 4);
    int*   dst_c  = (int*)  alloc((size_t)N_EDGES * 4);
    float* dist_c = (float*)alloc((size_t)N_EDGES * 4);
    float* sc_c   = (float*)alloc((size_t)N_EDGES * 4);
    ushort_t* Yfh = (ushort_t*)alloc((size_t)N_EDGES * 16 * 2);
    float* xiA  = (float*)alloc((size_t)N_NODES * DIM * 4);
    float* xiB  = (float*)alloc((size_t)N_NODES * DIM * 4);
    ushort_t* xib  = (ushort_t*)alloc((size_t)N_PAD * KQ * 2);
    ushort_t* cxm  = (ushort_t*)alloc((size_t)N_PAD * UI_W * 2);
    ushort_t* qh   = (ushort_t*)alloc((size_t)N_NODES * QK_W * 2);
    ushort_t* kh   = (ushort_t*)alloc((size_t)N_NODES * QK_W * 2);
    ushort_t* vh   = (ushort_t*)alloc((size_t)N_NODES * DIM * 2);
    float* ybuf    = (float*)alloc((size_t)N_NODES * DIM * 4);
    ushort_t* Wtq0 = (ushort_t*)alloc((size_t)832 * KQ * 2);
    ushort_t* Wtq1 = (ushort_t*)alloc((size_t)832 * KQ * 2);
    ushort_t* Wtu0 = (ushort_t*)alloc((size_t)192 * UI_W * 2);
    ushort_t* Wtu1 = (ushort_t*)alloc((size_t)192 * UI_W * 2);
    ushort_t* w1T0 = (ushort_t*)alloc((size_t)32 * 32 * 2);
    ushort_t* w2T0 = (ushort_t*)alloc((size_t)16 * 32 * 2);
    ushort_t* w1T1 = (ushort_t*)alloc((size_t)32 * 32 * 2);
    ushort_t* w2T1 = (ushort_t*)alloc((size_t)16 * 32 * 2);
    ushort_t* Vih  = (ushort_t*)alloc((size_t)N_NODES * 64 * 2);
    ushort_t* aijh = (ushort_t*)alloc((size_t)N_EDGES * NH * 2);

    const int NB_E  = (N_EDGES + 255) / 256;   // 1250
    const int NB_F  = N_EDGES / 64;            // 5000 (fused edge kernel)
    const int NB_T  = N_NODES / 16;            // 625
    const dim3 GRID_QKV(13, 157);
    const dim3 GRID_UPD(3, 157);

    hipMemsetAsync(deg, 0, (size_t)N_NODES * 4, stream);
    k_pre<<<3663, 256, 0, stream>>>(edst, esrc, dist, swit, vec, deg, rank, pk,
                                    wq0, wk0, wv0, Wtq0, wq1, wk1, wv1, Wtq1,
                                    uw0, Wtu0, uw1, Wtu1,
                                    pw1_0, pw2_0, w1T0, w2T0,
                                    pw1_1, pw2_1, w1T1, w2T1,
                                    species, z_table, wsp, xiA, xib, cxm);
    k_scan<<<1, 1024, 0, stream>>>(deg, off);
    k_perm<<<NB_E, 256, 0, stream>>>(edst, rank, off, perm);
    k_build<<<NB_E, 256, 0, stream>>>(perm, pk, src_c, dst_c, dist_c, sc_c, Yfh);

    // layer 0
    k_gemmq<<<GRID_QKV, 256, 0, stream>>>(xib, Wtq0, qh, kh, vh);
    k_edge<true><<<NB_F, 256, 0, stream>>>(dist_c, sc_c, src_c, dst_c, Yfh, Vih,
                                           qh, kh, w1T0, pb1_0, w2T0, pb2_0, aijh);
    k_agg0<<<5000, 256, 0, stream>>>(off, src_c, Yfh, aijh, vh, cxm, Vih);
    k_gemmu<<<GRID_UPD, 256, 0, stream>>>(cxm, Wtu0, ybuf);
    k_lnfinal<<<NB_T, 256, 0, stream>>>(ybuf, xiA, ub0, xiB, xib, cxm);

    // layer 1
    k_gemmq<<<GRID_QKV, 256, 0, stream>>>(xib, Wtq1, qh, kh, vh);
    k_edge<false><<<NB_F, 256, 0, stream>>>(dist_c, sc_c, src_c, dst_c, Yfh, Vih,
                                            qh, kh, w1T1, pb1_1, w2T1, pb2_1, aijh);
    k_agg1<<<2500, 256, 0, stream>>>(off, src_c, aijh, vh, cxm);
    k_gemmu<<<GRID_UPD, 256, 0, stream>>>(cxm, Wtu1, ybuf);
    k_lnfinal<<<NB_T, 256, 0, stream>>>(ybuf, xiB, ub1, out, xib, cxm);
}

// Round 11
// 356.923 us; speedup vs baseline: 1.0883x; 1.0000x over previous
//
#include <hip/hip_runtime.h>
#include <hip/hip_bf16.h>
#include <math.h>

#define N_NODES 10000
#define N_PAD   10048       // 157 * 64
#define N_EDGES 320000
#define DIM     176
#define ATT     16
#define SH_HEADS 16
#define THH     4
#define NH      20          // SH_HEADS + TH
#define VD      11          // DIM / SH_HEADS
#define ZDIM    16
#define RDIM    16
#define QK_W    (NH*ATT)    // 320
#define QKV_W   816         // 320+320+176
#define UI_W    (2*DIM)     // 352
#define KQ      192         // padded K for qkv gemm
#define SIGINV  3.5714285714285716f   // (RDIM-1)/(CUT-RSTART)
#define RSTEP   0.28f                 // (CUT-RSTART)/(RDIM-1)

typedef unsigned short ushort_t;
typedef __attribute__((ext_vector_type(8))) short bf16x8;
typedef __attribute__((ext_vector_type(4))) float f32x4;

// ---------------- helpers ----------------

__device__ __forceinline__ ushort_t f2bf(float f) {
    __hip_bfloat16 b = __float2bfloat16(f);
    return *(ushort_t*)&b;
}

__device__ __forceinline__ float bf2f(ushort_t u) {
    return __uint_as_float(((unsigned)u) << 16);
}

__device__ __forceinline__ void sph16(float x, float y, float z, float* Y) {
    const float s3  = 1.7320508075688772f;
    const float s15 = 3.872983346207417f;
    const float c1  = 0.7905694150420949f;
    const float c2  = 0.6123724356957945f;
    float x2 = x*x, y2 = y*y, z2 = z*z;
    Y[0]  = 1.0f;
    Y[1]  = x;
    Y[2]  = y;
    Y[3]  = z;
    Y[4]  = s3 * x * y;
    Y[5]  = s3 * y * z;
    Y[6]  = 0.5f * (3.0f * z2 - 1.0f);
    Y[7]  = s3 * x * z;
    Y[8]  = 0.5f * s3 * (x2 - y2);
    Y[9]  = c1 * y * (3.0f * x2 - y2);
    Y[10] = s15 * x * y * z;
    Y[11] = c2 * y * (5.0f * z2 - 1.0f);
    Y[12] = 0.5f * z * (5.0f * z2 - 3.0f);
    Y[13] = c2 * x * (5.0f * z2 - 1.0f);
    Y[14] = 0.5f * s15 * z * (x2 - y2);
    Y[15] = c1 * x * (x2 - 3.0f * y2);
}

__device__ __forceinline__ void unpack8(const uint4 u, float* f) {
    f[0] = __uint_as_float(u.x << 16);
    f[1] = __uint_as_float(u.x & 0xffff0000u);
    f[2] = __uint_as_float(u.y << 16);
    f[3] = __uint_as_float(u.y & 0xffff0000u);
    f[4] = __uint_as_float(u.z << 16);
    f[5] = __uint_as_float(u.z & 0xffff0000u);
    f[6] = __uint_as_float(u.w << 16);
    f[7] = __uint_as_float(u.w & 0xffff0000u);
}

// ---------------- merged prologue: deg+pack | weight prep | node embed ------

__device__ __forceinline__ void deg_body(int bid, int tid,
        const int* __restrict__ edst, const int* __restrict__ esrc,
        const float* __restrict__ dist, const float* __restrict__ swit,
        const float* __restrict__ vec, int* deg, int* rank, uint4* pk) {
    int e = bid * 256 + tid;
    if (e >= N_EDGES) return;
    int t_ = edst[e];
    rank[e] = atomicAdd(&deg[t_], 1);
    uint4 a, b;
    a.x = (unsigned)esrc[e];
    a.y = (unsigned)t_;
    a.z = __float_as_uint(dist[e]);
    a.w = __float_as_uint(swit[e]);
    b.x = __float_as_uint(vec[(size_t)e*3 + 0]);
    b.y = __float_as_uint(vec[(size_t)e*3 + 1]);
    b.z = __float_as_uint(vec[(size_t)e*3 + 2]);
    b.w = 0u;
    pk[(size_t)e*2 + 0] = a;
    pk[(size_t)e*2 + 1] = b;
}

__device__ __forceinline__ void prep_qkv_body(int bid, int tid, const float* wq,
        const float* wk, const float* wv, ushort_t* Wtq) {
    int id = bid * 256 + tid;
    if (id >= 832 * KQ) return;
    int n = id / KQ, k = id - (id / KQ) * KQ;
    float v = 0.0f;
    if (k < DIM && n < QKV_W)
        v = (n < 320) ? wq[k * 320 + n] : (n < 640) ? wk[k * 320 + (n - 320)]
                                                    : wv[k * DIM + (n - 640)];
    Wtq[id] = f2bf(v);
}

__device__ __forceinline__ void prep_upd_body(int bid, int tid, const float* uw, ushort_t* Wtu) {
    int id = bid * 256 + tid;
    if (id >= 192 * UI_W) return;
    int n = id / UI_W, k = id - (id / UI_W) * UI_W;
    float v = (n < DIM) ? uw[k * DIM + n] : 0.0f;
    Wtu[id] = f2bf(v);
}

__device__ __forceinline__ void prep_mlp_body(int bid, int tid, const float* pw1,
        const float* pw2, ushort_t* w1T, ushort_t* w2T, int K1) {
    int id = bid * 256 + tid;
    if (id < 1024) {
        int n = id >> 5, k = id & 31;
        w1T[n * 32 + k] = (k < K1) ? f2bf(pw1[k * 32 + n]) : 0;
    } else if (id < 1536) {
        int id2 = id - 1024;
        int n = id2 >> 5, k = id2 & 31;
        w2T[n * 32 + k] = f2bf(pw2[k * 16 + n]);
    }
}

struct InitSmem {
    float zs[16 * ZDIM];
    float yt[16 * DIM];
    float red[256];
    float mus[16], rstds[16];
};

__device__ void init_body(int bid, int tid, InitSmem& sm,
        const int* species, const float* z_table, const float* wsp,
        float* xi, ushort_t* xib, ushort_t* cxm) {
    int base = bid * 16;
    { int n = tid >> 4, kk = tid & 15;
      sm.zs[tid] = z_table[species[base + n] * ZDIM + kk]; }
    __syncthreads();
    int c = tid;
    if (c < DIM) {
        float acc[16];
        #pragma unroll
        for (int n = 0; n < 16; n++) acc[n] = 0.0f;
        for (int kk = 0; kk < ZDIM; kk++) {
            float w = wsp[kk * DIM + c];
            #pragma unroll
            for (int n = 0; n < 16; n++) acc[n] += sm.zs[n * ZDIM + kk] * w;
        }
        #pragma unroll
        for (int n = 0; n < 16; n++) sm.yt[n * DIM + c] = acc[n];
    }
    __syncthreads();
    { int n2 = tid >> 4, j = tid & 15;
      float s = 0.0f;
      for (int c2 = j; c2 < DIM; c2 += 16) s += sm.yt[n2 * DIM + c2];
      sm.red[tid] = s; }
    __syncthreads();
    if (tid < 16) { float s = 0; for (int j = 0; j < 16; j++) s += sm.red[tid * 16 + j]; sm.mus[tid] = s / (float)DIM; }
    __syncthreads();
    { int n2 = tid >> 4, j = tid & 15;
      float mu = sm.mus[n2], s = 0.0f;
      for (int c2 = j; c2 < DIM; c2 += 16) { float d = sm.yt[n2 * DIM + c2] - mu; s += d * d; }
      sm.red[tid] = s; }
    __syncthreads();
    if (tid < 16) { float s = 0; for (int j = 0; j < 16; j++) s += sm.red[tid * 16 + j]; sm.rstds[tid] = rsqrtf(s / (float)DIM + 1e-6f); }
    __syncthreads();
    if (c < DIM) {
        #pragma unroll
        for (int n = 0; n < 16; n++) {
            float val = (sm.yt[n * DIM + c] - sm.mus[n]) * sm.rstds[n];
            xi[(size_t)(base + n) * DIM + c] = val;
            ushort_t bv = f2bf(val);
            xib[(size_t)(base + n) * KQ + c]   = bv;
            cxm[(size_t)(base + n) * UI_W + c] = bv;
        }
    } else if (c < KQ) {
        #pragma unroll
        for (int n = 0; n < 16; n++) xib[(size_t)(base + n) * KQ + c] = 0;
    }
}

// grid = 1250 (deg) + 1788 (prep) + 625 (node init) = 3663
__global__ __launch_bounds__(256) void k_pre(
        const int* edst, const int* esrc, const float* dist, const float* swit,
        const float* vec, int* deg, int* rank, uint4* pk,
        const float* wq0, const float* wk0, const float* wv0, ushort_t* Wtq0,
        const float* wq1, const float* wk1, const float* wv1, ushort_t* Wtq1,
        const float* uw0, ushort_t* Wtu0, const float* uw1, ushort_t* Wtu1,
        const float* pw1_0, const float* pw2_0, ushort_t* w1T0, ushort_t* w2T0,
        const float* pw1_1, const float* pw2_1, ushort_t* w1T1, ushort_t* w2T1,
        const int* species, const float* z_table, const float* wsp,
        float* xi, ushort_t* xib, ushort_t* cxm) {
    __shared__ InitSmem sm;
    int bid = blockIdx.x, tid = threadIdx.x;
    if (bid < 1250)       deg_body(bid, tid, edst, esrc, dist, swit, vec, deg, rank, pk);
    else if (bid < 1874)  prep_qkv_body(bid - 1250, tid, wq0, wk0, wv0, Wtq0);
    else if (bid < 2498)  prep_qkv_body(bid - 1874, tid, wq1, wk1, wv1, Wtq1);
    else if (bid < 2762)  prep_upd_body(bid - 2498, tid, uw0, Wtu0);
    else if (bid < 3026)  prep_upd_body(bid - 2762, tid, uw1, Wtu1);
    else if (bid < 3032)  prep_mlp_body(bid - 3026, tid, pw1_0, pw2_0, w1T0, w2T0, 16);
    else if (bid < 3038)  prep_mlp_body(bid - 3032, tid, pw1_1, pw2_1, w1T1, w2T1, 32);
    else                  init_body(bid - 3038, tid, sm, species, z_table, wsp, xi, xib, cxm);
}

// ---------------- single-block scan (deg -> off) ----------------

__global__ __launch_bounds__(1024) void k_scan(const int* __restrict__ deg, int* off) {
    __shared__ int sd[1024];
    int tid = threadIdx.x;
    int base = tid * 10;
    int v[10];
    int s = 0;
    #pragma unroll
    for (int j = 0; j < 10; j++) {
        int gi = base + j;
        v[j] = (gi < N_NODES) ? deg[gi] : 0;
        s += v[j];
    }
    sd[tid] = s;
    __syncthreads();
    for (int st = 1; st < 1024; st <<= 1) {
        int add = (tid >= st) ? sd[tid - st] : 0;
        __syncthreads();
        sd[tid] += add;
        __syncthreads();
    }
    int run = (tid > 0) ? sd[tid - 1] : 0;
    #pragma unroll
    for (int j = 0; j < 10; j++) {
        run += v[j];
        int gi = base + j;
        if (gi < N_NODES) off[gi + 1] = run;
    }
    if (tid == 0) off[0] = 0;
}

// scatter ONLY the 4-byte permutation index (CSR slot -> original edge)
__global__ __launch_bounds__(256) void k_perm(const int* edst, const int* rank,
                                              const int* off, int* perm) {
    int e = blockIdx.x * 256 + threadIdx.x;
    if (e >= N_EDGES) return;
    perm[off[edst[e]] + rank[e]] = e;
}

// thread = CSR slot: ONE random aligned 32 B read, fully coalesced writes
// Yf stored as bf16 (16 x 2 B = 32 B per edge)
__global__ __launch_bounds__(256) void k_build(const int* __restrict__ perm,
        const uint4* __restrict__ pk,
        int* src_c, int* dst_c, float* dist_c, float* sc_c, ushort_t* Yfh) {
    int p = blockIdx.x * 256 + threadIdx.x;
    if (p >= N_EDGES) return;
    int e  = perm[p];
    uint4 a = pk[(size_t)e*2 + 0];
    uint4 b = pk[(size_t)e*2 + 1];
    int s  = (int)a.x;
    int t_ = (int)a.y;
    float d  = __uint_as_float(a.z);
    float sw = __uint_as_float(a.w);
    float inv = 1.0f / d;
    float vx = __uint_as_float(b.x) * inv;
    float vy = __uint_as_float(b.y) * inv;
    float vz = __uint_as_float(b.z) * inv;
    src_c[p]  = s;
    dst_c[p]  = t_;
    dist_c[p] = d;
    sc_c[p]   = sw * 0.25f;               // switch / sqrt(ATT)
    float Y[16];
    sph16(vx, vy, vz, Y);
    ushort_t yh[16];
    #pragma unroll
    for (int m = 0; m < 16; m++) yh[m] = f2bf(Y[m]);
    *(uint4*)&Yfh[(size_t)p * 16 + 0] = *(uint4*)&yh[0];
    *(uint4*)&Yfh[(size_t)p * 16 + 8] = *(uint4*)&yh[8];
}

// ---------------- MFMA GEMM (QKV, K=192, single-stage full-K tiles) --------

__global__ __launch_bounds__(256) void k_gemmq(const ushort_t* __restrict__ A,
                                               const ushort_t* __restrict__ Bt,
                                               ushort_t* __restrict__ qh,
                                               ushort_t* __restrict__ kh,
                                               ushort_t* __restrict__ vh) {
    __shared__ ushort_t As[64 * 200];
    __shared__ ushort_t Bs[64 * 200];
    int tid  = threadIdx.x;
    int m0   = blockIdx.y * 64, n0 = blockIdx.x * 64;
    int w    = tid >> 6, lane = tid & 63, quad = lane >> 4, c16 = lane & 15;
    #pragma unroll
    for (int it = 0; it < 6; it++) {
        int seg = it * 256 + tid;
        int r = seg / 24, cs = seg - (seg / 24) * 24;
        *(uint4*)&As[r * 200 + cs * 8] =
            *(const uint4*)&A[(size_t)(m0 + r) * KQ + cs * 8];
        *(uint4*)&Bs[r * 200 + cs * 8] =
            *(const uint4*)&Bt[(size_t)(n0 + r) * KQ + cs * 8];
    }
    __syncthreads();
    f32x4 acc[4] = {};
    #pragma unroll
    for (int kc = 0; kc < 6; kc++) {
        bf16x8 a = *(const bf16x8*)&As[(w * 16 + c16) * 200 + kc * 32 + quad * 8];
        #pragma unroll
        for (int t = 0; t < 4; t++) {
            bf16x8 b = *(const bf16x8*)&Bs[(t * 16 + c16) * 200 + kc * 32 + quad * 8];
            acc[t] = __builtin_amdgcn_mfma_f32_16x16x32_bf16(a, b, acc[t], 0, 0, 0);
        }
    }
    #pragma unroll
    for (int t = 0; t < 4; t++) {
        #pragma unroll
        for (int r = 0; r < 4; r++) {
            int row = m0 + w * 16 + quad * 4 + r;
            int col = n0 + t * 16 + c16;
            if (row < N_NODES && col < QKV_W) {
                ushort_t bv = f2bf(acc[t][r]);
                if (col < 320)      qh[(size_t)row * QK_W + col] = bv;
                else if (col < 640) kh[(size_t)row * QK_W + (col - 320)] = bv;
                else                vh[(size_t)row * DIM  + (col - 640)] = bv;
            }
        }
    }
}

// ---------------- MFMA GEMM (UPD, K=352, two-stage full-K tiles) ----------
// Output in bf16 (consumed only by LN; same quantization class as inputs).

__global__ __launch_bounds__(256) void k_gemmu(const ushort_t* __restrict__ A,
                                               const ushort_t* __restrict__ Bt,
                                               ushort_t* __restrict__ ybh) {
    __shared__ ushort_t As[64 * 200];
    __shared__ ushort_t Bs[64 * 200];
    int tid  = threadIdx.x;
    int m0   = blockIdx.y * 64, n0 = blockIdx.x * 64;
    int w    = tid >> 6, lane = tid & 63, quad = lane >> 4, c16 = lane & 15;
    f32x4 acc[4] = {};
    // ---- stage 1: K = 0..192 (24 uint4/row) ----
    #pragma unroll
    for (int it = 0; it < 6; it++) {
        int seg = it * 256 + tid;
        int r = seg / 24, cs = seg - (seg / 24) * 24;
        *(uint4*)&As[r * 200 + cs * 8] =
            *(const uint4*)&A[(size_t)(m0 + r) * UI_W + cs * 8];
        *(uint4*)&Bs[r * 200 + cs * 8] =
            *(const uint4*)&Bt[(size_t)(n0 + r) * UI_W + cs * 8];
    }
    __syncthreads();
    #pragma unroll
    for (int kc = 0; kc < 6; kc++) {
        bf16x8 a = *(const bf16x8*)&As[(w * 16 + c16) * 200 + kc * 32 + quad * 8];
        #pragma unroll
        for (int t = 0; t < 4; t++) {
            bf16x8 b = *(const bf16x8*)&Bs[(t * 16 + c16) * 200 + kc * 32 + quad * 8];
            acc[t] = __builtin_amdgcn_mfma_f32_16x16x32_bf16(a, b, acc[t], 0, 0, 0);
        }
    }
    __syncthreads();
    // ---- stage 2: K = 192..352 (20 uint4/row) ----
    #pragma unroll
    for (int it = 0; it < 5; it++) {
        int seg = it * 256 + tid;
        int r = seg / 20, cs = seg - (seg / 20) * 20;
        *(uint4*)&As[r * 200 + cs * 8] =
            *(const uint4*)&A[(size_t)(m0 + r) * UI_W + 192 + cs * 8];
        *(uint4*)&Bs[r * 200 + cs * 8] =
            *(const uint4*)&Bt[(size_t)(n0 + r) * UI_W + 192 + cs * 8];
    }
    __syncthreads();
    #pragma unroll
    for (int kc = 0; kc < 5; kc++) {
        bf16x8 a = *(const bf16x8*)&As[(w * 16 + c16) * 200 + kc * 32 + quad * 8];
        #pragma unroll
        for (int t = 0; t < 4; t++) {
            bf16x8 b = *(const bf16x8*)&Bs[(t * 16 + c16) * 200 + kc * 32 + quad * 8];
            acc[t] = __builtin_amdgcn_mfma_f32_16x16x32_bf16(a, b, acc[t], 0, 0, 0);
        }
    }
    #pragma unroll
    for (int t = 0; t < 4; t++) {
        #pragma unroll
        for (int r = 0; r < 4; r++) {
            int row = m0 + w * 16 + quad * 4 + r;
            int col = n0 + t * 16 + c16;
            if (row < N_NODES && col < DIM)
                ybh[(size_t)row * DIM + col] = f2bf(acc[t][r]);
        }
    }
}

// ---------------- fused edge kernel ----------------

template<bool L0>
__global__ __launch_bounds__(256) void k_edge(const float* dist_c, const float* sc_c,
        const int* src_c, const int* dst_c, const ushort_t* Yfh, const ushort_t* Vih,
        const ushort_t* qh, const ushort_t* kh,
        const ushort_t* w1T, const float* pb1, const ushort_t* w2T, const float* pb2,
        ushort_t* aijh) {
    __shared__ ushort_t urS[64 * 40];
    __shared__ ushort_t Ht[4][16 * 40];
    __shared__ float    wdS[64 * 17];
    __shared__ ushort_t aS[NH][64];
    int tid  = threadIdx.x;
    int w    = tid >> 6, lane = tid & 63, quad = lane >> 4, c16 = lane & 15;
    int eb   = blockIdx.x * 64;

    // aij-phase mapping (known at entry; only depends on src_c/dst_c)
    int le = tid >> 2, part = tid & 3;
    int ie = eb + le;
    int sE = src_c[ie], tE = dst_c[ie];

    if (!L0) {
        int e  = tid & 63, tp = tid >> 6;   // 4 threads/edge: tp = th component
        int i  = eb + e;
        float d = dist_c[i];
        ushort_t ur4[4];
        #pragma unroll
        for (int r0 = 0; r0 < 4; r0++) {
            int r = tp * 4 + r0;
            float cc = 0.8f + (float)r * RSTEP;
            float uu = (d - cc) * SIGINV;
            ur4[r0] = f2bf(__expf(-uu * uu));
        }
        *(uint2*)&urS[e * 40 + tp * 4] = *(uint2*)ur4;
        float Y[16];
        {
            uint4 y0 = *(const uint4*)&Yfh[(size_t)i * 16 + 0];
            uint4 y1 = *(const uint4*)&Yfh[(size_t)i * 16 + 8];
            unpack8(y0, Y);
            unpack8(y1, Y + 8);
        }
        int s = src_c[i], t_ = dst_c[i];
        const uint4* vd4 = (const uint4*)(Vih + (size_t)t_ * 64);
        const uint4* vs4 = (const uint4*)(Vih + (size_t)s  * 64);
        int th = tp;
        float fd[16], fs[16];
        unpack8(vd4[2*th],   fd);     unpack8(vd4[2*th+1], fd+8);
        unpack8(vs4[2*th],   fs);     unpack8(vs4[2*th+1], fs+8);
        float us0 = (fd[0] + fs[0]) * Y[0];
        float us1 = 0.0f, us2 = 0.0f, us3 = 0.0f;
        #pragma unroll
        for (int m = 1; m < 4; m++)  us1 += (fd[m] - fs[m]) * Y[m];
        #pragma unroll
        for (int m = 4; m < 9; m++)  us2 += (fd[m] + fs[m]) * Y[m];
        #pragma unroll
        for (int m = 9; m < 16; m++) us3 += (fd[m] - fs[m]) * Y[m];
        urS[e * 40 + 16 + 0 * 4 + th] = f2bf(us0);
        urS[e * 40 + 16 + 1 * 4 + th] = f2bf(us1);
        urS[e * 40 + 16 + 2 * 4 + th] = f2bf(us2);
        urS[e * 40 + 16 + 3 * 4 + th] = f2bf(us3);
        __syncthreads();
    }

    // ---- k prefetch: 160 B contiguous segment of k[src], 10 x uint4 ----
    uint4 kr[10];
    {
        const uint4* kseg = (const uint4*)(kh + (size_t)sE * QK_W) + part * 10;
        #pragma unroll
        for (int j = 0; j < 10; j++) kr[j] = kseg[j];
    }

    {
        int e0 = eb + w * 16;
        bf16x8 a1;
        if (L0) {
            float d = dist_c[e0 + c16];
            #pragma unroll
            for (int j = 0; j < 8; j++) {
                int r = quad * 8 + j;
                float v = 0.0f;
                if (r < 16) { float cc = 0.8f + (float)r * RSTEP; float uu = (d - cc) * SIGINV; v = __expf(-uu * uu); }
                a1[j] = (short)f2bf(v);
            }
        } else {
            a1 = *(const bf16x8*)&urS[(w * 16 + c16) * 40 + quad * 8];
        }
        bf16x8 b0 = *(const bf16x8*)&w1T[c16 * 32 + quad * 8];
        bf16x8 b1 = *(const bf16x8*)&w1T[(16 + c16) * 32 + quad * 8];
        f32x4 acc0 = {}, acc1 = {};
        acc0 = __builtin_amdgcn_mfma_f32_16x16x32_bf16(a1, b0, acc0, 0, 0, 0);
        acc1 = __builtin_amdgcn_mfma_f32_16x16x32_bf16(a1, b1, acc1, 0, 0, 0);
        float bb0 = pb1[c16], bb1 = pb1[c16 + 16];
        #pragma unroll
        for (int r = 0; r < 4; r++) {
            int er = quad * 4 + r;
            float h0 = acc0[r] + bb0; h0 = h0 / (1.0f + __expf(-h0));
            float h1 = acc1[r] + bb1; h1 = h1 / (1.0f + __expf(-h1));
            Ht[w][er * 40 + c16]      = f2bf(h0);
            Ht[w][er * 40 + 16 + c16] = f2bf(h1);
        }
        __syncthreads();
        bf16x8 a2 = *(const bf16x8*)&Ht[w][c16 * 40 + quad * 8];
        bf16x8 b2 = *(const bf16x8*)&w2T[c16 * 32 + quad * 8];
        f32x4 acc2 = {};
        acc2 = __builtin_amdgcn_mfma_f32_16x16x32_bf16(a2, b2, acc2, 0, 0, 0);
        float bb2 = pb2[c16];
        #pragma unroll
        for (int r = 0; r < 4; r++) {
            int er = quad * 4 + r;
            wdS[(w * 16 + er) * 17 + c16] = (acc2[r] + bb2) * sc_c[e0 + er];
        }
    }
    __syncthreads();

    {
        float wd[16];
        #pragma unroll
        for (int p = 0; p < 16; p++) wd[p] = wdS[le * 17 + p];
        const uint4* q4 = (const uint4*)(qh + (size_t)tE * QK_W) + part * 10;
        #pragma unroll
        for (int j = 0; j < 5; j++) {
            int h = part * 5 + j;
            float qa[8], qb[8], ka[8], kb[8];
            unpack8(q4[2*j],   qa); unpack8(q4[2*j+1], qb);
            unpack8(kr[2*j],   ka); unpack8(kr[2*j+1], kb);
            float acc = 0.0f;
            #pragma unroll
            for (int dd = 0; dd < 8; dd++) acc += qa[dd] * ka[dd] * wd[dd];
            #pragma unroll
            for (int dd = 0; dd < 8; dd++) acc += qb[dd] * kb[dd] * wd[8 + dd];
            aS[h][le] = f2bf(acc);
        }
    }
    __syncthreads();
    {
        const uint* aSw = (const uint*)aS;
        for (int idx = tid; idx < NH * 32; idx += 256) {
            int h = idx >> 5, w2 = idx & 31;
            *(uint*)(aijh + (size_t)h * N_EDGES + eb + w2 * 2) = aSw[h * 32 + w2];
        }
    }
}

// ---------------- aggregation: one wave per node for BOTH mi and Vi ----------

__device__ __forceinline__ void mi_step(int i, int c0, bool f1, bool f2,
        const int* src_c, const ushort_t* aA, const ushort_t* aB, const ushort_t* vh,
        float& acc0, float& acc1, float& acc2, float& acc3) {
    int s0 = src_c[i];
    uint2 v0 = *(const uint2*)(vh + (size_t)s0 * DIM + c0);
    float a00 = bf2f(aA[i]), a0B = bf2f(aB[i]);
    float g01 = f1 ? a0B : a00, g02 = f2 ? a0B : a00;
    acc0 += a00 * __uint_as_float(v0.x << 16);
    acc1 += g01 * __uint_as_float(v0.x & 0xffff0000u);
    acc2 += g02 * __uint_as_float(v0.y << 16);
    acc3 += a0B * __uint_as_float(v0.y & 0xffff0000u);
}

// software-pipelined: load chunk c+1 (srcs, v-rows, aij) while computing chunk c
__device__ __forceinline__ void mi_wave(int n, int lane, const int* off, const int* src_c,
        const ushort_t* aijh, const ushort_t* vh, ushort_t* cxm) {
    if (lane >= 44) return;
    int c0 = lane * 4;
    int hA = c0 / VD;
    int hB = (c0 + 3) / VD;
    bool f1 = ((c0 + 1) / VD) != hA;
    bool f2 = ((c0 + 2) / VD) != hA;
    const ushort_t* aA = aijh + (size_t)hA * N_EDGES;
    const ushort_t* aB = aijh + (size_t)hB * N_EDGES;
    int start = off[n], end = off[n + 1];
    float acc0 = 0, acc1 = 0, acc2 = 0, acc3 = 0;
    int cnt = end - start;
    int i = start;

#define MI_ACC(vv, av, bv) { \
    float aa = bf2f(av), ab = bf2f(bv); \
    float g1 = f1 ? ab : aa, g2 = f2 ? ab : aa; \
    acc0 += aa * __uint_as_float((vv).x << 16); \
    acc1 += g1 * __uint_as_float((vv).x & 0xffff0000u); \
    acc2 += g2 * __uint_as_float((vv).y << 16); \
    acc3 += ab * __uint_as_float((vv).y & 0xffff0000u); }

    if (cnt >= 4) {
        int iend = start + (cnt & ~3);
        int s0 = src_c[i], s1 = src_c[i+1], s2 = src_c[i+2], s3 = src_c[i+3];
        uint2 v0 = *(const uint2*)(vh + (size_t)s0 * DIM + c0);
        uint2 v1 = *(const uint2*)(vh + (size_t)s1 * DIM + c0);
        uint2 v2 = *(const uint2*)(vh + (size_t)s2 * DIM + c0);
        uint2 v3 = *(const uint2*)(vh + (size_t)s3 * DIM + c0);
        ushort_t pA0 = aA[i], pA1 = aA[i+1], pA2 = aA[i+2], pA3 = aA[i+3];
        ushort_t pB0 = aB[i], pB1 = aB[i+1], pB2 = aB[i+2], pB3 = aB[i+3];
        for (i += 4; i + 4 <= iend; i += 4) {
            int t0 = src_c[i], t1 = src_c[i+1], t2 = src_c[i+2], t3 = src_c[i+3];
            uint2 w0 = *(const uint2*)(vh + (size_t)t0 * DIM + c0);
            uint2 w1 = *(const uint2*)(vh + (size_t)t1 * DIM + c0);
            uint2 w2 = *(const uint2*)(vh + (size_t)t2 * DIM + c0);
            uint2 w3 = *(const uint2*)(vh + (size_t)t3 * DIM + c0);
            ushort_t qA0 = aA[i], qA1 = aA[i+1], qA2 = aA[i+2], qA3 = aA[i+3];
            ushort_t qB0 = aB[i], qB1 = aB[i+1], qB2 = aB[i+2], qB3 = aB[i+3];
            MI_ACC(v0, pA0, pB0); MI_ACC(v1, pA1, pB1);
            MI_ACC(v2, pA2, pB2); MI_ACC(v3, pA3, pB3);
            v0 = w0; v1 = w1; v2 = w2; v3 = w3;
            pA0 = qA0; pA1 = qA1; pA2 = qA2; pA3 = qA3;
            pB0 = qB0; pB1 = qB1; pB2 = qB2; pB3 = qB3;
        }
        MI_ACC(v0, pA0, pB0); MI_ACC(v1, pA1, pB1);
        MI_ACC(v2, pA2, pB2); MI_ACC(v3, pA3, pB3);
    }
    for (; i < end; i++)
        mi_step(i, c0, f1, f2, src_c, aA, aB, vh, acc0, acc1, acc2, acc3);
#undef MI_ACC
    ushort_t o[4] = {f2bf(acc0), f2bf(acc1), f2bf(acc2), f2bf(acc3)};
    *(uint2*)(cxm + (size_t)n * UI_W + DIM + c0) = *(uint2*)o;
}

// software-pipelined vi reduction (Yfh in bf16)
__device__ __forceinline__ void vi_wave(int n, int lane, const int* off,
        const ushort_t* Yfh, const ushort_t* aijh, ushort_t* Vih) {
    int th = lane >> 4, sm = lane & 15;
    const ushort_t* ah = aijh + (size_t)(SH_HEADS + th) * N_EDGES;
    int start = off[n], end = off[n + 1];
    float acc = 0.0f;
    int cnt = end - start;
    int i = start;
    if (cnt >= 4) {
        int iend = start + (cnt & ~3);
        float a0 = bf2f(ah[i]),   y0 = bf2f(Yfh[(size_t)i * 16 + sm]);
        float a1 = bf2f(ah[i+1]), y1 = bf2f(Yfh[(size_t)(i+1) * 16 + sm]);
        float a2 = bf2f(ah[i+2]), y2 = bf2f(Yfh[(size_t)(i+2) * 16 + sm]);
        float a3 = bf2f(ah[i+3]), y3 = bf2f(Yfh[(size_t)(i+3) * 16 + sm]);
        for (i += 4; i + 4 <= iend; i += 4) {
            float b0 = bf2f(ah[i]),   z0 = bf2f(Yfh[(size_t)i * 16 + sm]);
            float b1 = bf2f(ah[i+1]), z1 = bf2f(Yfh[(size_t)(i+1) * 16 + sm]);
            float b2 = bf2f(ah[i+2]), z2 = bf2f(Yfh[(size_t)(i+2) * 16 + sm]);
            float b3 = bf2f(ah[i+3]), z3 = bf2f(Yfh[(size_t)(i+3) * 16 + sm]);
            acc += a0 * y0 + a1 * y1 + a2 * y2 + a3 * y3;
            a0 = b0; a1 = b1; a2 = b2; a3 = b3;
            y0 = z0; y1 = z1; y2 = z2; y3 = z3;
        }
        acc += a0 * y0 + a1 * y1 + a2 * y2 + a3 * y3;
    }
    for (; i < end; i++)
        acc += bf2f(ah[i]) * bf2f(Yfh[(size_t)i * 16 + sm]);
    Vih[(size_t)n * 64 + lane] = f2bf(acc);
}

__global__ __launch_bounds__(256) void k_agg0(const int* off, const int* src_c,
        const ushort_t* Yfh, const ushort_t* aijh, const ushort_t* vh,
        ushort_t* cxm, ushort_t* Vih) {
    int wid  = blockIdx.x * 4 + (threadIdx.x >> 6);
    int lane = threadIdx.x & 63;
    if (wid < N_NODES)
        mi_wave(wid, lane, off, src_c, aijh, vh, cxm);
    else
        vi_wave(wid - N_NODES, lane, off, Yfh, aijh, Vih);
}

__global__ __launch_bounds__(256) void k_agg1(const int* off, const int* src_c,
        const ushort_t* aijh, const ushort_t* vh, ushort_t* cxm) {
    int wid  = blockIdx.x * 4 + (threadIdx.x >> 6);
    int lane = threadIdx.x & 63;
    mi_wave(wid, lane, off, src_c, aijh, vh, cxm);
}

// ---------------- LN epilogue (reads bf16 GEMM output; LAST skips aux) -----

template<bool LAST>
__global__ __launch_bounds__(256) void k_lnfinal(const ushort_t* ybh, const float* xi,
        const float* ub, float* xo, ushort_t* xib, ushort_t* cxm) {
    __shared__ float yt[16 * DIM];
    __shared__ float red[256];
    __shared__ float mus[16], rstds[16];
    int base = blockIdx.x * 16;
    int tid  = threadIdx.x;
    for (int idx = tid; idx < 16 * DIM; idx += 256) {
        int n = idx / DIM, c = idx - n * DIM;
        yt[idx] = xi[(size_t)(base + n) * DIM + c]
                + bf2f(ybh[(size_t)(base + n) * DIM + c]) + ub[c];
    }
    __syncthreads();
    { int n2 = tid >> 4, j = tid & 15;
      float s = 0.0f;
      for (int c2 = j; c2 < DIM; c2 += 16) s += yt[n2 * DIM + c2];
      red[tid] = s; }
    __syncthreads();
    if (tid < 16) { float s = 0; for (int j = 0; j < 16; j++) s += red[tid * 16 + j]; mus[tid] = s / (float)DIM; }
    __syncthreads();
    { int n2 = tid >> 4, j = tid & 15;
      float mu = mus[n2], s = 0.0f;
      for (int c2 = j; c2 < DIM; c2 += 16) { float d = yt[n2 * DIM + c2] - mu; s += d * d; }
      red[tid] = s; }
    __syncthreads();
    if (tid < 16) { float s = 0; for (int j = 0; j < 16; j++) s += red[tid * 16 + j]; rstds[tid] = rsqrtf(s / (float)DIM + 1e-6f); }
    __syncthreads();
    int c = tid;
    if (c < DIM) {
        #pragma unroll
        for (int n = 0; n < 16; n++) {
            float val = (yt[n * DIM + c] - mus[n]) * rstds[n];
            xo[(size_t)(base + n) * DIM + c] = val;
            if (!LAST) {
                ushort_t bv = f2bf(val);
                xib[(size_t)(base + n) * KQ + c]   = bv;
                cxm[(size_t)(base + n) * UI_W + c] = bv;
            }
        }
    } else if (c < KQ) {
        if (!LAST) {
            #pragma unroll
            for (int n = 0; n < 16; n++) xib[(size_t)(base + n) * KQ + c] = 0;
        }
    }
}

// ---------------- launch ----------------

extern "C" void kernel_launch(void* const* d_in, const int* in_sizes, int n_in,
                              void* d_out, int out_size, void* d_ws, size_t ws_size,
                              hipStream_t stream) {
    const int*   species = (const int*)  d_in[0];
    const float* dist    = (const float*)d_in[1];
    const float* swit    = (const float*)d_in[2];
    const int*   esrc    = (const int*)  d_in[3];
    const int*   edst    = (const int*)  d_in[4];
    const float* vec     = (const float*)d_in[5];
    const float* z_table = (const float*)d_in[6];
    const float* wsp     = (const float*)d_in[7];
    const float* pw1_0 = (const float*)d_in[8],  *pb1_0 = (const float*)d_in[9];
    const float* pw2_0 = (const float*)d_in[10], *pb2_0 = (const float*)d_in[11];
    const float* wq0 = (const float*)d_in[12], *wk0 = (const float*)d_in[13];
    const float* wv0 = (const float*)d_in[14], *uw0 = (const float*)d_in[15];
    const float* ub0 = (const float*)d_in[16];
    const float* pw1_1 = (const float*)d_in[17], *pb1_1 = (const float*)d_in[18];
    const float* pw2_1 = (const float*)d_in[19], *pb2_1 = (const float*)d_in[20];
    const float* wq1 = (const float*)d_in[21], *wk1 = (const float*)d_in[22];
    const float* wv1 = (const float*)d_in[23], *uw1 = (const float*)d_in[24];
    const float* ub1 = (const float*)d_in[25];
    float* out = (float*)d_out;

    char* p = (char*)d_ws;
    auto alloc = [&](size_t bytes) -> char* {
        char* r = p;
        p += (bytes + 255) & ~(size_t)255;
        return r;
    };
    int* deg    = (int*)alloc((size_t)N_NODES * 4);
    int* off    = (int*)alloc((size_t)(N_NODES + 1) * 4);
    int* rank   = (int*)alloc((size_t)N_EDGES * 4);
    int* perm   = (int*)alloc((size_t)N_EDGES * 4);
    uint4* pk   = (uint4*)alloc((size_t)N_EDGES * 32);
    int*   src_c  = (int*)  alloc((size_t)N_EDGES * 4);
    int*   dst_c  = (int*)  alloc((size_t)N_EDGES * 4);
    float* dist_c = (float*)alloc((size_t)N_EDGES * 4);
    float* sc_c   = (float*)alloc((size_t)N_EDGES * 4);
    ushort_t* Yfh = (ushort_t*)alloc((size_t)N_EDGES * 16 * 2);
    float* xiA  = (float*)alloc((size_t)N_NODES * DIM * 4);
    float* xiB  = (float*)alloc((size_t)N_NODES * DIM * 4);
    ushort_t* xib  = (ushort_t*)alloc((size_t)N_PAD * KQ * 2);
    ushort_t* cxm  = (ushort_t*)alloc((size_t)N_PAD * UI_W * 2);
    ushort_t* qh   = (ushort_t*)alloc((size_t)N_NODES * QK_W * 2);
    ushort_t* kh   = (ushort_t*)alloc((size_t)N_NODES * QK_W * 2);
    ushort_t* vh   = (ushort_t*)alloc((size_t)N_NODES * DIM * 2);
    ushort_t* ybh  = (ushort_t*)alloc((size_t)N_NODES * DIM * 2);
    ushort_t* Wtq0 = (ushort_t*)alloc((size_t)832 * KQ * 2);
    ushort_t* Wtq1 = (ushort_t*)alloc((size_t)832 * KQ * 2);
    ushort_t* Wtu0 = (ushort_t*)alloc((size_t)192 * UI_W * 2);
    ushort_t* Wtu1 = (ushort_t*)alloc((size_t)192 * UI_W * 2);
    ushort_t* w1T0 = (ushort_t*)alloc((size_t)32 * 32 * 2);
    ushort_t* w2T0 = (ushort_t*)alloc((size_t)16 * 32 * 2);
    ushort_t* w1T1 = (ushort_t*)alloc((size_t)32 * 32 * 2);
    ushort_t* w2T1 = (ushort_t*)alloc((size_t)16 * 32 * 2);
    ushort_t* Vih  = (ushort_t*)alloc((size_t)N_NODES * 64 * 2);
    ushort_t* aijh = (ushort_t*)alloc((size_t)N_EDGES * NH * 2);

    const int NB_E  = (N_EDGES + 255) / 256;   // 1250
    const int NB_F  = N_EDGES / 64;            // 5000 (fused edge kernel)
    const int NB_T  = N_NODES / 16;            // 625
    const dim3 GRID_QKV(13, 157);
    const dim3 GRID_UPD(3, 157);

    hipMemsetAsync(deg, 0, (size_t)N_NODES * 4, stream);
    k_pre<<<3663, 256, 0, stream>>>(edst, esrc, dist, swit, vec, deg, rank, pk,
                                    wq0, wk0, wv0, Wtq0, wq1, wk1, wv1, Wtq1,
                                    uw0, Wtu0, uw1, Wtu1,
                                    pw1_0, pw2_0, w1T0, w2T0,
                                    pw1_1, pw2_1, w1T1, w2T1,
                                    species, z_table, wsp, xiA, xib, cxm);
    k_scan<<<1, 1024, 0, stream>>>(deg, off);
    k_perm<<<NB_E, 256, 0, stream>>>(edst, rank, off, perm);
    k_build<<<NB_E, 256, 0, stream>>>(perm, pk, src_c, dst_c, dist_c, sc_c, Yfh);

    // layer 0
    k_gemmq<<<GRID_QKV, 256, 0, stream>>>(xib, Wtq0, qh, kh, vh);
    k_edge<true><<<NB_F, 256, 0, stream>>>(dist_c, sc_c, src_c, dst_c, Yfh, Vih,
                                           qh, kh, w1T0, pb1_0, w2T0, pb2_0, aijh);
    k_agg0<<<5000, 256, 0, stream>>>(off, src_c, Yfh, aijh, vh, cxm, Vih);
    k_gemmu<<<GRID_UPD, 256, 0, stream>>>(cxm, Wtu0, ybh);
    k_lnfinal<false><<<NB_T, 256, 0, stream>>>(ybh, xiA, ub0, xiB, xib, cxm);

    // layer 1
    k_gemmq<<<GRID_QKV, 256, 0, stream>>>(xib, Wtq1, qh, kh, vh);
    k_edge<false><<<NB_F, 256, 0, stream>>>(dist_c, sc_c, src_c, dst_c, Yfh, Vih,
                                            qh, kh, w1T1, pb1_1, w2T1, pb2_1, aijh);
    k_agg1<<<2500, 256, 0, stream>>>(off, src_c, aijh, vh, cxm);
    k_gemmu<<<GRID_UPD, 256, 0, stream>>>(cxm, Wtu1, ybh);
    k_lnfinal<true><<<NB_T, 256, 0, stream>>>(ybh, xiB, ub1, out, xib, cxm);
}